// Round 12
// baseline (925.552 us; speedup 1.0000x reference)
//
#include <hip/hip_runtime.h>
#include <hip/hip_bf16.h>

// GCN: 3x GCNConv(H=64) + global mean pool + linear head.
// Round 11 -> 12: float4 gather. A feature row (256B) = 16 lanes x float4, so
// one wave-wide load covers 4 edges (4x fewer vmem instrs, ~2x less VALU in
// the gather loop, same bytes). Quarter-wave partial accumulators merged by
// 2-step shfl_xor at the epilogue. CSR build (p1/p2), inline GEMM, pooling
// unchanged from R11.

#define WS_ALIGN(x) (((x) + 255) & ~size_t(255))
#define NCHUNK 8
#define NB 32            // dst rows per gather block
#define RPW (NB / 4)     // rows per wave
#define NBIN 256         // NB*NCHUNK fine bins per gather block
#define USH 17
#define UMASK 0x1FFFF
#define BKTMAX 256       // max superblocks (N <= 131072)
#define SBS 512          // dsts per superblock
#define SBKEYS 4096      // SBS * NCHUNK
#define P1T 2048         // edges per p1 tile

__global__ __launch_bounds__(256) void k_zero(int g, int e, int* bucketCnt,
                                              int* gCursor, int* csr,
                                              float* gsum, float* gcnt) {
    int i = blockIdx.x * blockDim.x + threadIdx.x;
    if (i < BKTMAX) { bucketCnt[i] = 0; gCursor[i] = 0; }
    if (i < g) { gsum[i] = 0.f; gcnt[i] = 0.f; }
    if (i < 4) csr[e + i] = 0;
}

__global__ __launch_bounds__(256) void k_cnt1(int e, const int* __restrict__ dst,
                                              int* __restrict__ bucketCnt) {
    __shared__ int c[BKTMAX];
    int tid = threadIdx.x;
    c[tid] = 0;
    __syncthreads();
    int base = blockIdx.x * P1T;
#pragma unroll
    for (int q = 0; q < P1T / 256; ++q) {
        int i = base + q * 256 + tid;
        if (i < e) atomicAdd(&c[dst[i] >> 9], 1);
    }
    __syncthreads();
    if (c[tid] > 0) atomicAdd(&bucketCnt[tid], c[tid]);
}

__global__ __launch_bounds__(256) void k_scanB(int nbkt, int e,
                                               const int* __restrict__ bucketCnt,
                                               int* __restrict__ bucketStart) {
    __shared__ int sd[256];
    int tid = threadIdx.x;
    int v = (tid < nbkt) ? bucketCnt[tid] : 0;
    sd[tid] = v;
    __syncthreads();
    for (int off = 1; off < 256; off <<= 1) {
        int t = (tid >= off) ? sd[tid - off] : 0;
        __syncthreads();
        sd[tid] += t;
        __syncthreads();
    }
    if (tid < nbkt) bucketStart[tid] = sd[tid] - v;
    if (tid == 0) bucketStart[nbkt] = e;
}

// p1: tile sort by superblock, contiguous run writes of packed words
__global__ __launch_bounds__(256) void k_p1(int e, const int* __restrict__ src,
                                            const int* __restrict__ dst,
                                            const int* __restrict__ bucketStart,
                                            int* __restrict__ gCursor,
                                            int* __restrict__ pkbuf) {
    __shared__ int cnt[BKTMAX], exc[BKTMAX], cur[BKTMAX], bb[BKTMAX];
    __shared__ int sd[256];
    __shared__ int stage[P1T];
    __shared__ unsigned char stgb[P1T];
    int tid = threadIdx.x;
    cnt[tid] = 0;
    __syncthreads();
    int base = blockIdx.x * P1T;
    int m = e - base; if (m > P1T) m = P1T;
    int pk8[P1T / 256];
    int b8[P1T / 256];
#pragma unroll
    for (int q = 0; q < P1T / 256; ++q) {
        int li = q * 256 + tid;
        if (li < m) {
            int d = dst[base + li];
            int s = src[base + li];
            int b = d >> 9;
            b8[q] = b;
            pk8[q] = ((d & (SBS - 1)) << USH) | s;
            atomicAdd(&cnt[b], 1);
        }
    }
    __syncthreads();
    int cv = cnt[tid];
    sd[tid] = cv;
    __syncthreads();
    for (int off = 1; off < 256; off <<= 1) {
        int t = (tid >= off) ? sd[tid - off] : 0;
        __syncthreads();
        sd[tid] += t;
        __syncthreads();
    }
    exc[tid] = sd[tid] - cv;
    cur[tid] = sd[tid] - cv;
    if (cv > 0) bb[tid] = atomicAdd(&gCursor[tid], cv);
    __syncthreads();
#pragma unroll
    for (int q = 0; q < P1T / 256; ++q) {
        int li = q * 256 + tid;
        if (li < m) {
            int b = b8[q];
            int pos = atomicAdd(&cur[b], 1);
            stage[pos] = pk8[q];
            stgb[pos] = (unsigned char)b;
        }
    }
    __syncthreads();
#pragma unroll
    for (int q = 0; q < P1T / 256; ++q) {
        int p = q * 256 + tid;
        if (p < m) {
            int b = stgb[p];
            pkbuf[bucketStart[b] + bb[b] + (p - exc[b])] = stage[p];
        }
    }
}

// p2: per-superblock counting sort -> csr [row][chunk] + bounds + dinv/xs
__global__ __launch_bounds__(256) void k_p2(int n, const int* __restrict__ bucketStart,
                                            const int* __restrict__ pkbuf,
                                            const float* __restrict__ x,
                                            int* __restrict__ csr,
                                            int* __restrict__ boundsG,
                                            float* __restrict__ dinv,
                                            float* __restrict__ xs) {
    __shared__ int cnt[SBKEYS + 1];
    __shared__ int sd[256];
    int sb = blockIdx.x, tid = threadIdx.x;
    int r0 = bucketStart[sb], r1 = bucketStart[sb + 1];
    for (int k = tid; k < SBKEYS + 1; k += 256) cnt[k] = 0;
    __syncthreads();
    for (int i = r0 + tid; i < r1; i += 256) {
        int w = pkbuf[i];
        int key = ((w >> USH) << 3) | ((w & UMASK) >> 14);
        atomicAdd(&cnt[key], 1);
    }
    __syncthreads();
    int base16 = tid * 16;
    int loc[16]; int s = 0;
#pragma unroll
    for (int j = 0; j < 16; ++j) { loc[j] = cnt[base16 + j]; s += loc[j]; }
    sd[tid] = s;
    __syncthreads();
    for (int off = 1; off < 256; off <<= 1) {
        int t = (tid >= off) ? sd[tid - off] : 0;
        __syncthreads();
        sd[tid] += t;
        __syncthreads();
    }
    int run = sd[tid] - s;
#pragma unroll
    for (int j = 0; j < 16; ++j) { cnt[base16 + j] = run; run += loc[j]; }
    if (tid == 255) cnt[SBKEYS] = run;
    __syncthreads();
    for (int k = tid; k < SBKEYS; k += 256) {
        int bi = sb * 16 + (k >> 8);
        boundsG[(size_t)bi * (NBIN + 1) + (k & 255)] = r0 + cnt[k];
    }
    if (tid < 16)
        boundsG[(size_t)(sb * 16 + tid) * (NBIN + 1) + NBIN] = r0 + cnt[(tid + 1) * 256];
    for (int dl = tid; dl < SBS; dl += 256) {
        int v = sb * SBS + dl;
        if (v < n) {
            int deg = cnt[dl * 8 + 8] - cnt[dl * 8] + 1;
            float di = 1.0f / sqrtf((float)deg);
            dinv[v] = di;
            xs[v] = x[v] * di;
        }
    }
    __syncthreads();
    for (int i = r0 + tid; i < r1; i += 256) {
        int w = pkbuf[i];
        int srcv = w & UMASK;
        int key = ((w >> USH) << 3) | (srcv >> 14);
        int pos = atomicAdd(&cnt[key], 1);
        csr[r0 + pos] = srcv;
    }
}

// layer 1 scalar gather, thread-per-row
__global__ __launch_bounds__(256) void k_s(int n, const int* __restrict__ boundsG,
                                           const int* __restrict__ csr,
                                           const float* __restrict__ xs,
                                           const float* __restrict__ dinv,
                                           float* __restrict__ s) {
    int v = blockIdx.x * blockDim.x + threadIdx.x;
    if (v >= n) return;
    int bi = v / NB, vi = v & (NB - 1);
    const int* B = &boundsG[(size_t)bi * (NBIN + 1)];
    int s0 = B[vi * NCHUNK];
    int s1 = B[vi * NCHUNK + NCHUNK];
    float a0 = 0.f, a1 = 0.f, a2 = 0.f, a3 = 0.f;
    int k = s0;
    for (; k + 4 <= s1; k += 4) {
        a0 += xs[csr[k]];
        a1 += xs[csr[k + 1]];
        a2 += xs[csr[k + 2]];
        a3 += xs[csr[k + 3]];
    }
    for (; k < s1; ++k) a0 += xs[csr[k]];
    s[v] = ((a0 + a1) + (a2 + a3) + xs[v]) * dinv[v];
}

__global__ __launch_bounds__(256) void k_h1(int n, const float* __restrict__ s,
                                            const float* __restrict__ dinv,
                                            const float* __restrict__ w1,
                                            const float* __restrict__ b1,
                                            float* __restrict__ hs) {
    int t = blockIdx.x * blockDim.x + threadIdx.x;
    if (t >= n * 64) return;
    int i = t >> 6, j = t & 63;
    float v = fmaxf(s[i] * w1[j] + b1[j], 0.f);
    hs[t] = v * dinv[i];
}

// ---- fused chunked-gather (float4: 4 edges/wave-load) + inline GEMM ----
// Each quarter-wave (16 lanes) owns one edge; lane loads float4 of the row.
// acc4[q] holds the quarter's partial; merged by shfl_xor(16,32) at epilogue.
#define GATHER_CORE_F4                                                         \
    __shared__ float ws[64 * 64];                                              \
    __shared__ float rowl[4][64];                                              \
    __shared__ int bndL[NBIN + 1];                                             \
    int tid = threadIdx.x;                                                     \
    int lane = tid & 63;                                                       \
    int r = tid >> 6;                                                          \
    int q4 = lane >> 4;                                                        \
    int fi = lane & 15;                                                        \
    int v0 = blockIdx.x * NB;                                                  \
    const float4* hs4 = (const float4*)hs_in;                                  \
    for (int k = tid; k < 64 * 64; k += 256) ws[k] = w[k];                     \
    bndL[tid] = boundsG[(size_t)blockIdx.x * (NBIN + 1) + tid];                \
    if (tid == 0) bndL[NBIN] = boundsG[(size_t)blockIdx.x * (NBIN + 1) + NBIN];\
    float4 acc4[RPW];                                                          \
    _Pragma("unroll")                                                          \
    for (int q = 0; q < RPW; ++q) {                                            \
        int v = v0 + q * 4 + r;                                                \
        if (v < n && q4 == 0) acc4[q] = hs4[(size_t)v * 16 + fi];              \
        else acc4[q] = make_float4(0.f, 0.f, 0.f, 0.f);                        \
    }                                                                          \
    __syncthreads();                                                           \
    for (int c = 0; c < NCHUNK; ++c) {                                         \
        _Pragma("unroll")                                                      \
        for (int t = 0; t < RPW / 2; ++t) {                                    \
            int viA = (2 * t) * 4 + r;                                         \
            int viB = (2 * t + 1) * 4 + r;                                     \
            int a0 = __builtin_amdgcn_readfirstlane(bndL[viA * NCHUNK + c]);   \
            int a1 = __builtin_amdgcn_readfirstlane(bndL[viA * NCHUNK + c + 1]);\
            int b0_ = __builtin_amdgcn_readfirstlane(bndL[viB * NCHUNK + c]);  \
            int b1_ = __builtin_amdgcn_readfirstlane(bndL[viB * NCHUNK + c + 1]);\
            int ba = a0, bb = b0_;                                             \
            while (ba < a1 || bb < b1_) {                                      \
                int remA = a1 - ba;                                            \
                int remB = b1_ - bb;                                           \
                int pa = (remA > 0) ? ba : bb;                                 \
                int pb = (remB > 0) ? bb : ba;                                 \
                int uA0 = csr[pa],     uA1 = csr[pa + 1];                      \
                int uA2 = csr[pa + 2], uA3 = csr[pa + 3];                      \
                int uB0 = csr[pb],     uB1 = csr[pb + 1];                      \
                int uB2 = csr[pb + 2], uB3 = csr[pb + 3];                      \
                int uA = (q4 & 1) ? uA1 : uA0;                                 \
                int uAh = (q4 & 1) ? uA3 : uA2;                                \
                uA = (q4 & 2) ? uAh : uA;                                      \
                int uB = (q4 & 1) ? uB1 : uB0;                                 \
                int uBh = (q4 & 1) ? uB3 : uB2;                                \
                uB = (q4 & 2) ? uBh : uB;                                      \
                float4 gA = hs4[(size_t)uA * 16 + fi];                         \
                float4 gB = hs4[(size_t)uB * 16 + fi];                         \
                float mA = (q4 < remA) ? 1.f : 0.f;                            \
                float mB = (q4 < remB) ? 1.f : 0.f;                            \
                acc4[2 * t].x += gA.x * mA; acc4[2 * t].y += gA.y * mA;        \
                acc4[2 * t].z += gA.z * mA; acc4[2 * t].w += gA.w * mA;        \
                acc4[2 * t + 1].x += gB.x * mB; acc4[2 * t + 1].y += gB.y * mB;\
                acc4[2 * t + 1].z += gB.z * mB; acc4[2 * t + 1].w += gB.w * mB;\
                ba += 4; bb += 4;                                              \
            }                                                                  \
        }                                                                      \
        __syncthreads();                                                       \
    }

__global__ __launch_bounds__(256, 8) void k_gg_mid(int n,
                                                   const int* __restrict__ boundsG,
                                                   const int* __restrict__ csr,
                                                   const float* __restrict__ hs_in,
                                                   const float* __restrict__ dinv,
                                                   const float* __restrict__ w,
                                                   const float* __restrict__ b,
                                                   float* __restrict__ hs_out) {
    GATHER_CORE_F4
    float breg = b[lane];
#pragma unroll 1
    for (int q = 0; q < RPW; ++q) {
        int v = v0 + q * 4 + r;
        if (v >= n) continue;
        float dv = dinv[v];
        float4 a4 = acc4[q];
        a4.x += __shfl_xor(a4.x, 16, 64); a4.y += __shfl_xor(a4.y, 16, 64);
        a4.z += __shfl_xor(a4.z, 16, 64); a4.w += __shfl_xor(a4.w, 16, 64);
        a4.x += __shfl_xor(a4.x, 32, 64); a4.y += __shfl_xor(a4.y, 32, 64);
        a4.z += __shfl_xor(a4.z, 32, 64); a4.w += __shfl_xor(a4.w, 32, 64);
        if (q4 == 0) {
            float4* rl4 = (float4*)&rowl[r][0];
            rl4[fi] = make_float4(a4.x * dv, a4.y * dv, a4.z * dv, a4.w * dv);
        }
        float o = breg;
#pragma unroll
        for (int k = 0; k < 64; ++k) o += rowl[r][k] * ws[k * 64 + lane];
        hs_out[(size_t)v * 64 + lane] = fmaxf(o, 0.f) * dv;
    }
}

__global__ __launch_bounds__(256, 8) void k_gg_final(int n,
                                                     const int* __restrict__ boundsG,
                                                     const int* __restrict__ csr,
                                                     const float* __restrict__ hs_in,
                                                     const float* __restrict__ dinv,
                                                     const float* __restrict__ w,
                                                     const float* __restrict__ b,
                                                     const float* __restrict__ fcw,
                                                     float* __restrict__ dots) {
    GATHER_CORE_F4
    float breg = b[lane];
    float freg = fcw[lane];
#pragma unroll 1
    for (int q = 0; q < RPW; ++q) {
        int v = v0 + q * 4 + r;
        if (v >= n) continue;
        float dv = dinv[v];
        float4 a4 = acc4[q];
        a4.x += __shfl_xor(a4.x, 16, 64); a4.y += __shfl_xor(a4.y, 16, 64);
        a4.z += __shfl_xor(a4.z, 16, 64); a4.w += __shfl_xor(a4.w, 16, 64);
        a4.x += __shfl_xor(a4.x, 32, 64); a4.y += __shfl_xor(a4.y, 32, 64);
        a4.z += __shfl_xor(a4.z, 32, 64); a4.w += __shfl_xor(a4.w, 32, 64);
        if (q4 == 0) {
            float4* rl4 = (float4*)&rowl[r][0];
            rl4[fi] = make_float4(a4.x * dv, a4.y * dv, a4.z * dv, a4.w * dv);
        }
        float o = breg;
#pragma unroll
        for (int k = 0; k < 64; ++k) o += rowl[r][k] * ws[k * 64 + lane];
        float val = fmaxf(o, 0.f) * freg;
#pragma unroll
        for (int m = 32; m > 0; m >>= 1) val += __shfl_xor(val, m, 64);
        if (lane == 0) dots[v] = val;
    }
}

// pooled accumulation: LDS-binned segmented reduce over sorted batch
__global__ __launch_bounds__(256) void k_pool(int n, const float* __restrict__ dots,
                                              const int* __restrict__ batch,
                                              float* __restrict__ gsum,
                                              float* __restrict__ gcnt) {
    __shared__ float ls[64], lc[64];
    __shared__ int gmin_s;
    int tid = threadIdx.x;
    int i0 = blockIdx.x * 1024;
    if (tid == 0) gmin_s = batch[i0];
    if (tid < 64) { ls[tid] = 0.f; lc[tid] = 0.f; }
    __syncthreads();
    int gmin = gmin_s;
#pragma unroll
    for (int c = 0; c < 4; ++c) {
        int i = i0 + c * 256 + tid;
        if (i < n) {
            int g = batch[i];
            float d = dots[i];
            int rr = g - gmin;
            if (rr < 64) {
                atomicAdd(&ls[rr], d);
                atomicAdd(&lc[rr], 1.f);
            } else {
                atomicAdd(&gsum[g], d);
                atomicAdd(&gcnt[g], 1.f);
            }
        }
    }
    __syncthreads();
    if (tid < 64 && lc[tid] != 0.f) {
        atomicAdd(&gsum[gmin + tid], ls[tid]);
        atomicAdd(&gcnt[gmin + tid], lc[tid]);
    }
}

__global__ __launch_bounds__(256) void k_out(int g, const float* __restrict__ gsum,
                                             const float* __restrict__ gcnt,
                                             const float* __restrict__ fcb,
                                             float* __restrict__ out) {
    int i = blockIdx.x * blockDim.x + threadIdx.x;
    if (i < g) out[i] = gsum[i] / fmaxf(gcnt[i], 1.f) + fcb[0];
}

extern "C" void kernel_launch(void* const* d_in, const int* in_sizes, int n_in,
                              void* d_out, int out_size, void* d_ws, size_t ws_size,
                              hipStream_t stream) {
    const float* x    = (const float*)d_in[0];
    const int*   ei   = (const int*)d_in[1];
    const int*   batch= (const int*)d_in[2];
    const float* w1   = (const float*)d_in[3];
    const float* b1   = (const float*)d_in[4];
    const float* w2   = (const float*)d_in[5];
    const float* b2   = (const float*)d_in[6];
    const float* w3   = (const float*)d_in[7];
    const float* b3   = (const float*)d_in[8];
    const float* fcw  = (const float*)d_in[9];
    const float* fcb  = (const float*)d_in[10];
    float* out = (float*)d_out;

    const int N = in_sizes[0];           // needs N <= 131072 (17-bit packing)
    const int E = in_sizes[1] / 2;
    const int G = out_size;
    const int H = 64;
    const int nbkt = (N + SBS - 1) / SBS;        // 196 superblocks
    const int NBLK = (N + NB - 1) / NB;          // 3125 gather blocks
    const int NBLKP = nbkt * 16;                 // padded bounds rows

    const int* src = ei;
    const int* dst = ei + E;

    char* p = (char*)d_ws;
    int*   bucketCnt   = (int*)p; p += WS_ALIGN(sizeof(int) * BKTMAX);
    int*   bucketStart = (int*)p; p += WS_ALIGN(sizeof(int) * (BKTMAX + 1));
    int*   gCursor     = (int*)p; p += WS_ALIGN(sizeof(int) * BKTMAX);
    int*   pkbuf       = (int*)p; p += WS_ALIGN(sizeof(int) * (size_t)E);
    int*   csr         = (int*)p; p += WS_ALIGN(sizeof(int) * ((size_t)E + 4));
    int*   boundsG     = (int*)p; p += WS_ALIGN(sizeof(int) * (size_t)NBLKP * (NBIN + 1));
    float* dinv        = (float*)p; p += WS_ALIGN(sizeof(float) * N);
    float* xs          = (float*)p; p += WS_ALIGN(sizeof(float) * N);
    float* sbuf        = (float*)p; p += WS_ALIGN(sizeof(float) * N);
    float* bufA        = (float*)p; p += WS_ALIGN(sizeof(float) * (size_t)N * H);
    float* bufB        = (float*)p; p += WS_ALIGN(sizeof(float) * (size_t)N * H);
    float* dots        = (float*)p; p += WS_ALIGN(sizeof(float) * N);
    float* gsum        = (float*)p; p += WS_ALIGN(sizeof(float) * G);
    float* gcnt        = (float*)p; p += WS_ALIGN(sizeof(float) * G);

    const int B = 256;
    int gridZ    = ((G > BKTMAX ? G : BKTMAX) + B - 1) / B;
    int gridT    = (E + P1T - 1) / P1T;
    int gridRow  = (N + B - 1) / B;
    int gridNH   = (N * H + B - 1) / B;
    int gridG    = (G + B - 1) / B;
    int gridPool = (N + 1023) / 1024;

    k_zero<<<gridZ, B, 0, stream>>>(G, E, bucketCnt, gCursor, csr, gsum, gcnt);
    k_cnt1<<<gridT, B, 0, stream>>>(E, dst, bucketCnt);
    k_scanB<<<1, B, 0, stream>>>(nbkt, E, bucketCnt, bucketStart);
    k_p1<<<gridT, B, 0, stream>>>(E, src, dst, bucketStart, gCursor, pkbuf);
    k_p2<<<nbkt, B, 0, stream>>>(N, bucketStart, pkbuf, x, csr, boundsG, dinv, xs);
    // layer 1 (rank-1)
    k_s<<<gridRow, B, 0, stream>>>(N, boundsG, csr, xs, dinv, sbuf);
    k_h1<<<gridNH, B, 0, stream>>>(N, sbuf, dinv, w1, b1, bufA);
    // layer 2: fused gather + GEMM(w2) -> bufB
    k_gg_mid<<<NBLK, B, 0, stream>>>(N, boundsG, csr, bufA, dinv, w2, b2, bufB);
    // layer 3: fused gather + GEMM(w3) + fc dot -> dots
    k_gg_final<<<NBLK, B, 0, stream>>>(N, boundsG, csr, bufB, dinv, w3, b3, fcw, dots);
    // pooling + head
    k_pool<<<gridPool, B, 0, stream>>>(N, dots, batch, gsum, gcnt);
    k_out<<<gridG, B, 0, stream>>>(G, gsum, gcnt, fcb, out);
}

// Round 13
// 512.756 us; speedup vs baseline: 1.8051x; 1.8051x over previous
//
#include <hip/hip_runtime.h>
#include <hip/hip_bf16.h>

// GCN: 3x GCNConv(H=64) + global mean pool + linear head.
// Round 12 -> 13: REVERT to R11 scalar-gather core (R12's float4 acc spilled
// to scratch under launch_bounds(256,8): WRITE_SIZE 3.5MB->790MB).
// Changes vs R11: NCHUNK 8->16 (1.6MB src slice, stops per-XCD L2 thrash
// seen as 398MB vs ~250MB expected FETCH) and k_s+k_h1 fused into a
// persistent wave-per-node layer-1 kernel.

#define WS_ALIGN(x) (((x) + 255) & ~size_t(255))
#define NCHUNK 16
#define CSH 13           // chunk = src >> 13 (8192-node chunks, N <= 131072)
#define NB 32            // dst rows per gather block
#define RPW (NB / 4)     // rows per wave
#define NBIN (NB * NCHUNK)   // 512 fine bins per gather block
#define USH 17
#define UMASK 0x1FFFF
#define BKTMAX 256       // max superblocks (N <= 131072)
#define SBS 512          // dsts per superblock
#define SBKEYS (SBS * NCHUNK)   // 8192
#define P1T 2048         // edges per p1 tile

__global__ __launch_bounds__(256) void k_zero(int g, int e, int* bucketCnt,
                                              int* gCursor, int* csr,
                                              float* gsum, float* gcnt) {
    int i = blockIdx.x * blockDim.x + threadIdx.x;
    if (i < BKTMAX) { bucketCnt[i] = 0; gCursor[i] = 0; }
    if (i < g) { gsum[i] = 0.f; gcnt[i] = 0.f; }
    if (i < 4) csr[e + i] = 0;
}

__global__ __launch_bounds__(256) void k_cnt1(int e, const int* __restrict__ dst,
                                              int* __restrict__ bucketCnt) {
    __shared__ int c[BKTMAX];
    int tid = threadIdx.x;
    c[tid] = 0;
    __syncthreads();
    int base = blockIdx.x * P1T;
#pragma unroll
    for (int q = 0; q < P1T / 256; ++q) {
        int i = base + q * 256 + tid;
        if (i < e) atomicAdd(&c[dst[i] >> 9], 1);
    }
    __syncthreads();
    if (c[tid] > 0) atomicAdd(&bucketCnt[tid], c[tid]);
}

__global__ __launch_bounds__(256) void k_scanB(int nbkt, int e,
                                               const int* __restrict__ bucketCnt,
                                               int* __restrict__ bucketStart) {
    __shared__ int sd[256];
    int tid = threadIdx.x;
    int v = (tid < nbkt) ? bucketCnt[tid] : 0;
    sd[tid] = v;
    __syncthreads();
    for (int off = 1; off < 256; off <<= 1) {
        int t = (tid >= off) ? sd[tid - off] : 0;
        __syncthreads();
        sd[tid] += t;
        __syncthreads();
    }
    if (tid < nbkt) bucketStart[tid] = sd[tid] - v;
    if (tid == 0) bucketStart[nbkt] = e;
}

// p1: tile sort by superblock, contiguous run writes of packed words
__global__ __launch_bounds__(256) void k_p1(int e, const int* __restrict__ src,
                                            const int* __restrict__ dst,
                                            const int* __restrict__ bucketStart,
                                            int* __restrict__ gCursor,
                                            int* __restrict__ pkbuf) {
    __shared__ int cnt[BKTMAX], exc[BKTMAX], cur[BKTMAX], bb[BKTMAX];
    __shared__ int sd[256];
    __shared__ int stage[P1T];
    __shared__ unsigned char stgb[P1T];
    int tid = threadIdx.x;
    cnt[tid] = 0;
    __syncthreads();
    int base = blockIdx.x * P1T;
    int m = e - base; if (m > P1T) m = P1T;
    int pk8[P1T / 256];
    int b8[P1T / 256];
#pragma unroll
    for (int q = 0; q < P1T / 256; ++q) {
        int li = q * 256 + tid;
        if (li < m) {
            int d = dst[base + li];
            int s = src[base + li];
            int b = d >> 9;
            b8[q] = b;
            pk8[q] = ((d & (SBS - 1)) << USH) | s;
            atomicAdd(&cnt[b], 1);
        }
    }
    __syncthreads();
    int cv = cnt[tid];
    sd[tid] = cv;
    __syncthreads();
    for (int off = 1; off < 256; off <<= 1) {
        int t = (tid >= off) ? sd[tid - off] : 0;
        __syncthreads();
        sd[tid] += t;
        __syncthreads();
    }
    exc[tid] = sd[tid] - cv;
    cur[tid] = sd[tid] - cv;
    if (cv > 0) bb[tid] = atomicAdd(&gCursor[tid], cv);
    __syncthreads();
#pragma unroll
    for (int q = 0; q < P1T / 256; ++q) {
        int li = q * 256 + tid;
        if (li < m) {
            int b = b8[q];
            int pos = atomicAdd(&cur[b], 1);
            stage[pos] = pk8[q];
            stgb[pos] = (unsigned char)b;
        }
    }
    __syncthreads();
#pragma unroll
    for (int q = 0; q < P1T / 256; ++q) {
        int p = q * 256 + tid;
        if (p < m) {
            int b = stgb[p];
            pkbuf[bucketStart[b] + bb[b] + (p - exc[b])] = stage[p];
        }
    }
}

// p2: per-superblock counting sort -> csr [row][chunk] + bounds + dinv/xs
__global__ __launch_bounds__(256) void k_p2(int n, const int* __restrict__ bucketStart,
                                            const int* __restrict__ pkbuf,
                                            const float* __restrict__ x,
                                            int* __restrict__ csr,
                                            int* __restrict__ boundsG,
                                            float* __restrict__ dinv,
                                            float* __restrict__ xs) {
    __shared__ int cnt[SBKEYS + 1];
    __shared__ int sd[256];
    int sb = blockIdx.x, tid = threadIdx.x;
    int r0 = bucketStart[sb], r1 = bucketStart[sb + 1];
    for (int k = tid; k < SBKEYS + 1; k += 256) cnt[k] = 0;
    __syncthreads();
    // phase A: count keys (key = dstLow*16 + chunk)
    for (int i = r0 + tid; i < r1; i += 256) {
        int w = pkbuf[i];
        int key = ((w >> USH) << 4) | ((w & UMASK) >> CSH);
        atomicAdd(&cnt[key], 1);
    }
    __syncthreads();
    // phase B: in-place exclusive scan (32 keys/thread)
    int base32 = tid * 32;
    int loc[32]; int s = 0;
#pragma unroll
    for (int j = 0; j < 32; ++j) { loc[j] = cnt[base32 + j]; s += loc[j]; }
    sd[tid] = s;
    __syncthreads();
    for (int off = 1; off < 256; off <<= 1) {
        int t = (tid >= off) ? sd[tid - off] : 0;
        __syncthreads();
        sd[tid] += t;
        __syncthreads();
    }
    int run = sd[tid] - s;
#pragma unroll
    for (int j = 0; j < 32; ++j) { cnt[base32 + j] = run; run += loc[j]; }
    if (tid == 255) cnt[SBKEYS] = run;
    __syncthreads();
    // bounds (16 gather blocks per superblock, NBIN=512 bins each)
    for (int k = tid; k < SBKEYS; k += 256) {
        int bi = sb * 16 + (k >> 9);
        boundsG[(size_t)bi * (NBIN + 1) + (k & 511)] = r0 + cnt[k];
    }
    if (tid < 16)
        boundsG[(size_t)(sb * 16 + tid) * (NBIN + 1) + NBIN] = r0 + cnt[(tid + 1) * 512];
    for (int dl = tid; dl < SBS; dl += 256) {
        int v = sb * SBS + dl;
        if (v < n) {
            int deg = cnt[dl * 16 + 16] - cnt[dl * 16] + 1;
            float di = 1.0f / sqrtf((float)deg);
            dinv[v] = di;
            xs[v] = x[v] * di;
        }
    }
    __syncthreads();
    // phase C: place (cnt doubles as cursor); block owns csr[r0..r1)
    for (int i = r0 + tid; i < r1; i += 256) {
        int w = pkbuf[i];
        int srcv = w & UMASK;
        int key = ((w >> USH) << 4) | (srcv >> CSH);
        int pos = atomicAdd(&cnt[key], 1);
        csr[r0 + pos] = srcv;
    }
}

// layer 1 fused (rank-1), persistent wave-per-node:
// hs1[v][j] = relu(((sum xs[u] + xs[v])*dinv)*w1[j] + b1[j]) * dinv
__global__ __launch_bounds__(256, 8) void k_layer1(int n, const int* __restrict__ boundsG,
                                                   const int* __restrict__ csr,
                                                   const float* __restrict__ xs,
                                                   const float* __restrict__ dinv,
                                                   const float* __restrict__ w1,
                                                   const float* __restrict__ b1,
                                                   float* __restrict__ hs_out) {
    int tid = threadIdx.x;
    int r = tid >> 6, lane = tid & 63;
    float w1r = w1[lane], b1r = b1[lane];
    int wid = blockIdx.x * 4 + r;
    int stride = gridDim.x * 4;
    for (int v = wid; v < n; v += stride) {
        int bi = v / NB, vi = v & (NB - 1);
        size_t base = (size_t)bi * (NBIN + 1) + vi * NCHUNK;
        int s0 = boundsG[base], s1 = boundsG[base + NCHUNK];  // row contiguous
        float acc = 0.f;
        for (int k = s0 + lane; k < s1; k += 64) acc += xs[csr[k]];
#pragma unroll
        for (int m = 32; m > 0; m >>= 1) acc += __shfl_xor(acc, m, 64);
        float dv = dinv[v];
        float s = (acc + xs[v]) * dv;
        hs_out[(size_t)v * 64 + lane] = fmaxf(s * w1r + b1r, 0.f) * dv;
    }
}

// ---- fused chunked-gather + inline GEMM (R11 scalar structure) ----
#define GATHER_CORE                                                            \
    __shared__ float ws[64 * 64];                                              \
    __shared__ float rowl[4][64];                                              \
    __shared__ int bndL[NBIN + 1];                                             \
    int tid = threadIdx.x;                                                     \
    int lane = tid & 63;                                                       \
    int r = tid >> 6;                                                          \
    int v0 = blockIdx.x * NB;                                                  \
    for (int k = tid; k < 64 * 64; k += 256) ws[k] = w[k];                     \
    for (int i = tid; i < NBIN + 1; i += 256)                                  \
        bndL[i] = boundsG[(size_t)blockIdx.x * (NBIN + 1) + i];                \
    float acc[RPW];                                                            \
    _Pragma("unroll")                                                          \
    for (int q = 0; q < RPW; ++q) {                                            \
        int v = v0 + q * 4 + r;                                                \
        acc[q] = (v < n) ? hs_in[(size_t)v * 64 + lane] : 0.f;                 \
    }                                                                          \
    __syncthreads();                                                           \
    for (int c = 0; c < NCHUNK; ++c) {                                         \
        _Pragma("unroll")                                                      \
        for (int t = 0; t < RPW / 2; ++t) {                                    \
            int viA = (2 * t) * 4 + r;                                         \
            int viB = (2 * t + 1) * 4 + r;                                     \
            int a0 = __builtin_amdgcn_readfirstlane(bndL[viA * NCHUNK + c]);   \
            int a1 = __builtin_amdgcn_readfirstlane(bndL[viA * NCHUNK + c + 1]);\
            int b0_ = __builtin_amdgcn_readfirstlane(bndL[viB * NCHUNK + c]);  \
            int b1_ = __builtin_amdgcn_readfirstlane(bndL[viB * NCHUNK + c + 1]);\
            int ba = a0, bb = b0_;                                             \
            while (ba < a1 || bb < b1_) {                                      \
                int remA = a1 - ba;                                            \
                int remB = b1_ - bb;                                           \
                int pa = (remA > 0) ? ba : bb;                                 \
                int pb = (remB > 0) ? bb : ba;                                 \
                int uA0 = csr[pa],     uA1 = csr[pa + 1];                      \
                int uA2 = csr[pa + 2], uA3 = csr[pa + 3];                      \
                int uB0 = csr[pb],     uB1 = csr[pb + 1];                      \
                int uB2 = csr[pb + 2], uB3 = csr[pb + 3];                      \
                float gA0 = hs_in[(size_t)uA0 * 64 + lane];                    \
                float gA1 = hs_in[(size_t)uA1 * 64 + lane];                    \
                float gA2 = hs_in[(size_t)uA2 * 64 + lane];                    \
                float gA3 = hs_in[(size_t)uA3 * 64 + lane];                    \
                float gB0 = hs_in[(size_t)uB0 * 64 + lane];                    \
                float gB1 = hs_in[(size_t)uB1 * 64 + lane];                    \
                float gB2 = hs_in[(size_t)uB2 * 64 + lane];                    \
                float gB3 = hs_in[(size_t)uB3 * 64 + lane];                    \
                if (remA >= 4) acc[2 * t] += (gA0 + gA1) + (gA2 + gA3);        \
                else if (remA > 0) {                                           \
                    acc[2 * t] += gA0;                                         \
                    if (remA > 1) acc[2 * t] += gA1;                           \
                    if (remA > 2) acc[2 * t] += gA2;                           \
                }                                                              \
                if (remB >= 4) acc[2 * t + 1] += (gB0 + gB1) + (gB2 + gB3);    \
                else if (remB > 0) {                                           \
                    acc[2 * t + 1] += gB0;                                     \
                    if (remB > 1) acc[2 * t + 1] += gB1;                       \
                    if (remB > 2) acc[2 * t + 1] += gB2;                       \
                }                                                              \
                ba += 4; bb += 4;                                              \
            }                                                                  \
        }                                                                      \
        __syncthreads();                                                       \
    }

__global__ __launch_bounds__(256, 8) void k_gg_mid(int n,
                                                   const int* __restrict__ boundsG,
                                                   const int* __restrict__ csr,
                                                   const float* __restrict__ hs_in,
                                                   const float* __restrict__ dinv,
                                                   const float* __restrict__ w,
                                                   const float* __restrict__ b,
                                                   float* __restrict__ hs_out) {
    GATHER_CORE
    float breg = b[lane];
#pragma unroll 1
    for (int q = 0; q < RPW; ++q) {
        int v = v0 + q * 4 + r;
        if (v >= n) continue;
        float dv = dinv[v];
        rowl[r][lane] = acc[q] * dv;
        float o = breg;
#pragma unroll
        for (int k = 0; k < 64; ++k) o += rowl[r][k] * ws[k * 64 + lane];
        hs_out[(size_t)v * 64 + lane] = fmaxf(o, 0.f) * dv;
    }
}

__global__ __launch_bounds__(256, 8) void k_gg_final(int n,
                                                     const int* __restrict__ boundsG,
                                                     const int* __restrict__ csr,
                                                     const float* __restrict__ hs_in,
                                                     const float* __restrict__ dinv,
                                                     const float* __restrict__ w,
                                                     const float* __restrict__ b,
                                                     const float* __restrict__ fcw,
                                                     float* __restrict__ dots) {
    GATHER_CORE
    float breg = b[lane];
    float freg = fcw[lane];
#pragma unroll 1
    for (int q = 0; q < RPW; ++q) {
        int v = v0 + q * 4 + r;
        if (v >= n) continue;
        float dv = dinv[v];
        rowl[r][lane] = acc[q] * dv;
        float o = breg;
#pragma unroll
        for (int k = 0; k < 64; ++k) o += rowl[r][k] * ws[k * 64 + lane];
        float val = fmaxf(o, 0.f) * freg;
#pragma unroll
        for (int m = 32; m > 0; m >>= 1) val += __shfl_xor(val, m, 64);
        if (lane == 0) dots[v] = val;
    }
}

// pooled accumulation: LDS-binned segmented reduce over sorted batch
__global__ __launch_bounds__(256) void k_pool(int n, const float* __restrict__ dots,
                                              const int* __restrict__ batch,
                                              float* __restrict__ gsum,
                                              float* __restrict__ gcnt) {
    __shared__ float ls[64], lc[64];
    __shared__ int gmin_s;
    int tid = threadIdx.x;
    int i0 = blockIdx.x * 1024;
    if (tid == 0) gmin_s = batch[i0];
    if (tid < 64) { ls[tid] = 0.f; lc[tid] = 0.f; }
    __syncthreads();
    int gmin = gmin_s;
#pragma unroll
    for (int c = 0; c < 4; ++c) {
        int i = i0 + c * 256 + tid;
        if (i < n) {
            int g = batch[i];
            float d = dots[i];
            int rr = g - gmin;
            if (rr < 64) {
                atomicAdd(&ls[rr], d);
                atomicAdd(&lc[rr], 1.f);
            } else {
                atomicAdd(&gsum[g], d);
                atomicAdd(&gcnt[g], 1.f);
            }
        }
    }
    __syncthreads();
    if (tid < 64 && lc[tid] != 0.f) {
        atomicAdd(&gsum[gmin + tid], ls[tid]);
        atomicAdd(&gcnt[gmin + tid], lc[tid]);
    }
}

__global__ __launch_bounds__(256) void k_out(int g, const float* __restrict__ gsum,
                                             const float* __restrict__ gcnt,
                                             const float* __restrict__ fcb,
                                             float* __restrict__ out) {
    int i = blockIdx.x * blockDim.x + threadIdx.x;
    if (i < g) out[i] = gsum[i] / fmaxf(gcnt[i], 1.f) + fcb[0];
}

extern "C" void kernel_launch(void* const* d_in, const int* in_sizes, int n_in,
                              void* d_out, int out_size, void* d_ws, size_t ws_size,
                              hipStream_t stream) {
    const float* x    = (const float*)d_in[0];
    const int*   ei   = (const int*)d_in[1];
    const int*   batch= (const int*)d_in[2];
    const float* w1   = (const float*)d_in[3];
    const float* b1   = (const float*)d_in[4];
    const float* w2   = (const float*)d_in[5];
    const float* b2   = (const float*)d_in[6];
    const float* w3   = (const float*)d_in[7];
    const float* b3   = (const float*)d_in[8];
    const float* fcw  = (const float*)d_in[9];
    const float* fcb  = (const float*)d_in[10];
    float* out = (float*)d_out;

    const int N = in_sizes[0];           // needs N <= 131072 (17-bit packing)
    const int E = in_sizes[1] / 2;
    const int G = out_size;
    const int H = 64;
    const int nbkt = (N + SBS - 1) / SBS;        // 196 superblocks
    const int NBLK = (N + NB - 1) / NB;          // 3125 gather blocks
    const int NBLKP = nbkt * 16;                 // padded bounds rows

    const int* src = ei;
    const int* dst = ei + E;

    char* p = (char*)d_ws;
    int*   bucketCnt   = (int*)p; p += WS_ALIGN(sizeof(int) * BKTMAX);
    int*   bucketStart = (int*)p; p += WS_ALIGN(sizeof(int) * (BKTMAX + 1));
    int*   gCursor     = (int*)p; p += WS_ALIGN(sizeof(int) * BKTMAX);
    int*   pkbuf       = (int*)p; p += WS_ALIGN(sizeof(int) * (size_t)E);
    int*   csr         = (int*)p; p += WS_ALIGN(sizeof(int) * ((size_t)E + 4));
    int*   boundsG     = (int*)p; p += WS_ALIGN(sizeof(int) * (size_t)NBLKP * (NBIN + 1));
    float* dinv        = (float*)p; p += WS_ALIGN(sizeof(float) * N);
    float* xs          = (float*)p; p += WS_ALIGN(sizeof(float) * N);
    float* bufA        = (float*)p; p += WS_ALIGN(sizeof(float) * (size_t)N * H);
    float* bufB        = (float*)p; p += WS_ALIGN(sizeof(float) * (size_t)N * H);
    float* dots        = (float*)p; p += WS_ALIGN(sizeof(float) * N);
    float* gsum        = (float*)p; p += WS_ALIGN(sizeof(float) * G);
    float* gcnt        = (float*)p; p += WS_ALIGN(sizeof(float) * G);

    const int B = 256;
    int gridZ    = ((G > BKTMAX ? G : BKTMAX) + B - 1) / B;
    int gridT    = (E + P1T - 1) / P1T;
    int gridG    = (G + B - 1) / B;
    int gridPool = (N + 1023) / 1024;
    int gridPers = 2048;
    if (gridPers * 4 > N) gridPers = (N + 3) / 4;

    k_zero<<<gridZ, B, 0, stream>>>(G, E, bucketCnt, gCursor, csr, gsum, gcnt);
    k_cnt1<<<gridT, B, 0, stream>>>(E, dst, bucketCnt);
    k_scanB<<<1, B, 0, stream>>>(nbkt, E, bucketCnt, bucketStart);
    k_p1<<<gridT, B, 0, stream>>>(E, src, dst, bucketStart, gCursor, pkbuf);
    k_p2<<<nbkt, B, 0, stream>>>(N, bucketStart, pkbuf, x, csr, boundsG, dinv, xs);
    // layer 1 (rank-1, fused persistent)
    k_layer1<<<gridPers, B, 0, stream>>>(N, boundsG, csr, xs, dinv, w1, b1, bufA);
    // layer 2: fused gather + GEMM(w2) -> bufB
    k_gg_mid<<<NBLK, B, 0, stream>>>(N, boundsG, csr, bufA, dinv, w2, b2, bufB);
    // layer 3: fused gather + GEMM(w3) + fc dot -> dots
    k_gg_final<<<NBLK, B, 0, stream>>>(N, boundsG, csr, bufB, dinv, w3, b3, fcw, dots);
    // pooling + head
    k_pool<<<gridPool, B, 0, stream>>>(N, dots, batch, gsum, gcnt);
    k_out<<<gridG, B, 0, stream>>>(G, gsum, gcnt, fcb, out);
}

// Round 14
// 464.384 us; speedup vs baseline: 1.9931x; 1.1042x over previous
//
#include <hip/hip_runtime.h>
#include <hip/hip_bf16.h>

// GCN: 3x GCNConv(H=64) + global mean pool + linear head.
// Round 13 -> 14: revert to exact R11 core (NCHUNK=8; 155us/gg proven).
// Keep R13's persistent fused layer-1. Single experiment: 4-row interleave
// in the gather inner loop (16 loads in flight vs 8) — doubles per-wave MLP
// at unchanged traffic. Register budget ~50-60 VGPR < 64 cap of (256,8).

#define WS_ALIGN(x) (((x) + 255) & ~size_t(255))
#define NCHUNK 8
#define CSH 14           // chunk = src >> 14 (R11 scheme)
#define NB 32            // dst rows per gather block
#define RPW (NB / 4)     // rows per wave = 8
#define NBIN (NB * NCHUNK)   // 256
#define USH 17
#define UMASK 0x1FFFF
#define BKTMAX 256
#define SBS 512
#define SBKEYS (SBS * NCHUNK)   // 4096
#define P1T 2048

__global__ __launch_bounds__(256) void k_zero(int g, int e, int* bucketCnt,
                                              int* gCursor, int* csr,
                                              float* gsum, float* gcnt) {
    int i = blockIdx.x * blockDim.x + threadIdx.x;
    if (i < BKTMAX) { bucketCnt[i] = 0; gCursor[i] = 0; }
    if (i < g) { gsum[i] = 0.f; gcnt[i] = 0.f; }
    if (i < 4) csr[e + i] = 0;
}

__global__ __launch_bounds__(256) void k_cnt1(int e, const int* __restrict__ dst,
                                              int* __restrict__ bucketCnt) {
    __shared__ int c[BKTMAX];
    int tid = threadIdx.x;
    c[tid] = 0;
    __syncthreads();
    int base = blockIdx.x * P1T;
#pragma unroll
    for (int q = 0; q < P1T / 256; ++q) {
        int i = base + q * 256 + tid;
        if (i < e) atomicAdd(&c[dst[i] >> 9], 1);
    }
    __syncthreads();
    if (c[tid] > 0) atomicAdd(&bucketCnt[tid], c[tid]);
}

__global__ __launch_bounds__(256) void k_scanB(int nbkt, int e,
                                               const int* __restrict__ bucketCnt,
                                               int* __restrict__ bucketStart) {
    __shared__ int sd[256];
    int tid = threadIdx.x;
    int v = (tid < nbkt) ? bucketCnt[tid] : 0;
    sd[tid] = v;
    __syncthreads();
    for (int off = 1; off < 256; off <<= 1) {
        int t = (tid >= off) ? sd[tid - off] : 0;
        __syncthreads();
        sd[tid] += t;
        __syncthreads();
    }
    if (tid < nbkt) bucketStart[tid] = sd[tid] - v;
    if (tid == 0) bucketStart[nbkt] = e;
}

// p1: tile sort by superblock, contiguous run writes of packed words
__global__ __launch_bounds__(256) void k_p1(int e, const int* __restrict__ src,
                                            const int* __restrict__ dst,
                                            const int* __restrict__ bucketStart,
                                            int* __restrict__ gCursor,
                                            int* __restrict__ pkbuf) {
    __shared__ int cnt[BKTMAX], exc[BKTMAX], cur[BKTMAX], bb[BKTMAX];
    __shared__ int sd[256];
    __shared__ int stage[P1T];
    __shared__ unsigned char stgb[P1T];
    int tid = threadIdx.x;
    cnt[tid] = 0;
    __syncthreads();
    int base = blockIdx.x * P1T;
    int m = e - base; if (m > P1T) m = P1T;
    int pk8[P1T / 256];
    int b8[P1T / 256];
#pragma unroll
    for (int q = 0; q < P1T / 256; ++q) {
        int li = q * 256 + tid;
        if (li < m) {
            int d = dst[base + li];
            int s = src[base + li];
            int b = d >> 9;
            b8[q] = b;
            pk8[q] = ((d & (SBS - 1)) << USH) | s;
            atomicAdd(&cnt[b], 1);
        }
    }
    __syncthreads();
    int cv = cnt[tid];
    sd[tid] = cv;
    __syncthreads();
    for (int off = 1; off < 256; off <<= 1) {
        int t = (tid >= off) ? sd[tid - off] : 0;
        __syncthreads();
        sd[tid] += t;
        __syncthreads();
    }
    exc[tid] = sd[tid] - cv;
    cur[tid] = sd[tid] - cv;
    if (cv > 0) bb[tid] = atomicAdd(&gCursor[tid], cv);
    __syncthreads();
#pragma unroll
    for (int q = 0; q < P1T / 256; ++q) {
        int li = q * 256 + tid;
        if (li < m) {
            int b = b8[q];
            int pos = atomicAdd(&cur[b], 1);
            stage[pos] = pk8[q];
            stgb[pos] = (unsigned char)b;
        }
    }
    __syncthreads();
#pragma unroll
    for (int q = 0; q < P1T / 256; ++q) {
        int p = q * 256 + tid;
        if (p < m) {
            int b = stgb[p];
            pkbuf[bucketStart[b] + bb[b] + (p - exc[b])] = stage[p];
        }
    }
}

// p2: per-superblock counting sort -> csr [row][chunk] + bounds + dinv/xs
__global__ __launch_bounds__(256) void k_p2(int n, const int* __restrict__ bucketStart,
                                            const int* __restrict__ pkbuf,
                                            const float* __restrict__ x,
                                            int* __restrict__ csr,
                                            int* __restrict__ boundsG,
                                            float* __restrict__ dinv,
                                            float* __restrict__ xs) {
    __shared__ int cnt[SBKEYS + 1];
    __shared__ int sd[256];
    int sb = blockIdx.x, tid = threadIdx.x;
    int r0 = bucketStart[sb], r1 = bucketStart[sb + 1];
    for (int k = tid; k < SBKEYS + 1; k += 256) cnt[k] = 0;
    __syncthreads();
    for (int i = r0 + tid; i < r1; i += 256) {
        int w = pkbuf[i];
        int key = ((w >> USH) << 3) | ((w & UMASK) >> CSH);
        atomicAdd(&cnt[key], 1);
    }
    __syncthreads();
    int base16 = tid * 16;
    int loc[16]; int s = 0;
#pragma unroll
    for (int j = 0; j < 16; ++j) { loc[j] = cnt[base16 + j]; s += loc[j]; }
    sd[tid] = s;
    __syncthreads();
    for (int off = 1; off < 256; off <<= 1) {
        int t = (tid >= off) ? sd[tid - off] : 0;
        __syncthreads();
        sd[tid] += t;
        __syncthreads();
    }
    int run = sd[tid] - s;
#pragma unroll
    for (int j = 0; j < 16; ++j) { cnt[base16 + j] = run; run += loc[j]; }
    if (tid == 255) cnt[SBKEYS] = run;
    __syncthreads();
    for (int k = tid; k < SBKEYS; k += 256) {
        int bi = sb * 16 + (k >> 8);
        boundsG[(size_t)bi * (NBIN + 1) + (k & 255)] = r0 + cnt[k];
    }
    if (tid < 16)
        boundsG[(size_t)(sb * 16 + tid) * (NBIN + 1) + NBIN] = r0 + cnt[(tid + 1) * 256];
    for (int dl = tid; dl < SBS; dl += 256) {
        int v = sb * SBS + dl;
        if (v < n) {
            int deg = cnt[dl * 8 + 8] - cnt[dl * 8] + 1;
            float di = 1.0f / sqrtf((float)deg);
            dinv[v] = di;
            xs[v] = x[v] * di;
        }
    }
    __syncthreads();
    for (int i = r0 + tid; i < r1; i += 256) {
        int w = pkbuf[i];
        int srcv = w & UMASK;
        int key = ((w >> USH) << 3) | (srcv >> CSH);
        int pos = atomicAdd(&cnt[key], 1);
        csr[r0 + pos] = srcv;
    }
}

// layer 1 fused (rank-1), persistent wave-per-node
__global__ __launch_bounds__(256, 8) void k_layer1(int n, const int* __restrict__ boundsG,
                                                   const int* __restrict__ csr,
                                                   const float* __restrict__ xs,
                                                   const float* __restrict__ dinv,
                                                   const float* __restrict__ w1,
                                                   const float* __restrict__ b1,
                                                   float* __restrict__ hs_out) {
    int tid = threadIdx.x;
    int r = tid >> 6, lane = tid & 63;
    float w1r = w1[lane], b1r = b1[lane];
    int wid = blockIdx.x * 4 + r;
    int stride = gridDim.x * 4;
    for (int v = wid; v < n; v += stride) {
        int bi = v / NB, vi = v & (NB - 1);
        size_t base = (size_t)bi * (NBIN + 1) + vi * NCHUNK;
        int s0 = boundsG[base], s1 = boundsG[base + NCHUNK];  // row contiguous
        float acc = 0.f;
        for (int k = s0 + lane; k < s1; k += 64) acc += xs[csr[k]];
#pragma unroll
        for (int m = 32; m > 0; m >>= 1) acc += __shfl_xor(acc, m, 64);
        float dv = dinv[v];
        float s = (acc + xs[v]) * dv;
        hs_out[(size_t)v * 64 + lane] = fmaxf(s * w1r + b1r, 0.f) * dv;
    }
}

// ---- fused chunked-gather + inline GEMM; 4-row interleave (16 loads in flight)
#define GATHER_CORE                                                            \
    __shared__ float ws[64 * 64];                                              \
    __shared__ float rowl[4][64];                                              \
    __shared__ int bndL[NBIN + 1];                                             \
    int tid = threadIdx.x;                                                     \
    int lane = tid & 63;                                                       \
    int r = tid >> 6;                                                          \
    int v0 = blockIdx.x * NB;                                                  \
    for (int k = tid; k < 64 * 64; k += 256) ws[k] = w[k];                     \
    for (int i = tid; i < NBIN + 1; i += 256)                                  \
        bndL[i] = boundsG[(size_t)blockIdx.x * (NBIN + 1) + i];                \
    float acc[RPW];                                                            \
    _Pragma("unroll")                                                          \
    for (int q = 0; q < RPW; ++q) {                                            \
        int v = v0 + q * 4 + r;                                                \
        acc[q] = (v < n) ? hs_in[(size_t)v * 64 + lane] : 0.f;                 \
    }                                                                          \
    __syncthreads();                                                           \
    for (int c = 0; c < NCHUNK; ++c) {                                         \
        _Pragma("unroll")                                                      \
        for (int t = 0; t < RPW / 4; ++t) {                                    \
            int viA = (4 * t + 0) * 4 + r;                                     \
            int viB = (4 * t + 1) * 4 + r;                                     \
            int viC = (4 * t + 2) * 4 + r;                                     \
            int viD = (4 * t + 3) * 4 + r;                                     \
            int eA0 = __builtin_amdgcn_readfirstlane(bndL[viA * NCHUNK + c]);  \
            int eA1 = __builtin_amdgcn_readfirstlane(bndL[viA * NCHUNK + c + 1]);\
            int eB0 = __builtin_amdgcn_readfirstlane(bndL[viB * NCHUNK + c]);  \
            int eB1 = __builtin_amdgcn_readfirstlane(bndL[viB * NCHUNK + c + 1]);\
            int eC0 = __builtin_amdgcn_readfirstlane(bndL[viC * NCHUNK + c]);  \
            int eC1 = __builtin_amdgcn_readfirstlane(bndL[viC * NCHUNK + c + 1]);\
            int eD0 = __builtin_amdgcn_readfirstlane(bndL[viD * NCHUNK + c]);  \
            int eD1 = __builtin_amdgcn_readfirstlane(bndL[viD * NCHUNK + c + 1]);\
            int ba = eA0, bb = eB0, bc = eC0, bd = eD0;                        \
            while ((ba < eA1) | (bb < eB1) | (bc < eC1) | (bd < eD1)) {        \
                int remA = eA1 - ba, remB = eB1 - bb;                          \
                int remC = eC1 - bc, remD = eD1 - bd;                          \
                int pA = (remA > 0) ? ba : ((remB > 0) ? bb : ((remC > 0) ? bc : bd)); \
                int pB = (remB > 0) ? bb : ((remA > 0) ? ba : ((remD > 0) ? bd : bc)); \
                int pC = (remC > 0) ? bc : ((remD > 0) ? bd : ((remA > 0) ? ba : bb)); \
                int pD = (remD > 0) ? bd : ((remC > 0) ? bc : ((remB > 0) ? bb : ba)); \
                int uA0 = csr[pA],     uA1 = csr[pA + 1];                      \
                int uA2 = csr[pA + 2], uA3 = csr[pA + 3];                      \
                int uB0 = csr[pB],     uB1 = csr[pB + 1];                      \
                int uB2 = csr[pB + 2], uB3 = csr[pB + 3];                      \
                int uC0 = csr[pC],     uC1 = csr[pC + 1];                      \
                int uC2 = csr[pC + 2], uC3 = csr[pC + 3];                      \
                int uD0 = csr[pD],     uD1 = csr[pD + 1];                      \
                int uD2 = csr[pD + 2], uD3 = csr[pD + 3];                      \
                float gA0 = hs_in[(size_t)uA0 * 64 + lane];                    \
                float gA1 = hs_in[(size_t)uA1 * 64 + lane];                    \
                float gA2 = hs_in[(size_t)uA2 * 64 + lane];                    \
                float gA3 = hs_in[(size_t)uA3 * 64 + lane];                    \
                float gB0 = hs_in[(size_t)uB0 * 64 + lane];                    \
                float gB1 = hs_in[(size_t)uB1 * 64 + lane];                    \
                float gB2 = hs_in[(size_t)uB2 * 64 + lane];                    \
                float gB3 = hs_in[(size_t)uB3 * 64 + lane];                    \
                float gC0 = hs_in[(size_t)uC0 * 64 + lane];                    \
                float gC1 = hs_in[(size_t)uC1 * 64 + lane];                    \
                float gC2 = hs_in[(size_t)uC2 * 64 + lane];                    \
                float gC3 = hs_in[(size_t)uC3 * 64 + lane];                    \
                float gD0 = hs_in[(size_t)uD0 * 64 + lane];                    \
                float gD1 = hs_in[(size_t)uD1 * 64 + lane];                    \
                float gD2 = hs_in[(size_t)uD2 * 64 + lane];                    \
                float gD3 = hs_in[(size_t)uD3 * 64 + lane];                    \
                if (remA >= 4) acc[4 * t + 0] += (gA0 + gA1) + (gA2 + gA3);    \
                else if (remA > 0) {                                           \
                    acc[4 * t + 0] += gA0;                                     \
                    if (remA > 1) acc[4 * t + 0] += gA1;                       \
                    if (remA > 2) acc[4 * t + 0] += gA2;                       \
                }                                                              \
                if (remB >= 4) acc[4 * t + 1] += (gB0 + gB1) + (gB2 + gB3);    \
                else if (remB > 0) {                                           \
                    acc[4 * t + 1] += gB0;                                     \
                    if (remB > 1) acc[4 * t + 1] += gB1;                       \
                    if (remB > 2) acc[4 * t + 1] += gB2;                       \
                }                                                              \
                if (remC >= 4) acc[4 * t + 2] += (gC0 + gC1) + (gC2 + gC3);    \
                else if (remC > 0) {                                           \
                    acc[4 * t + 2] += gC0;                                     \
                    if (remC > 1) acc[4 * t + 2] += gC1;                       \
                    if (remC > 2) acc[4 * t + 2] += gC2;                       \
                }                                                              \
                if (remD >= 4) acc[4 * t + 3] += (gD0 + gD1) + (gD2 + gD3);    \
                else if (remD > 0) {                                           \
                    acc[4 * t + 3] += gD0;                                     \
                    if (remD > 1) acc[4 * t + 3] += gD1;                       \
                    if (remD > 2) acc[4 * t + 3] += gD2;                       \
                }                                                              \
                ba += 4; bb += 4; bc += 4; bd += 4;                            \
            }                                                                  \
        }                                                                      \
        __syncthreads();                                                       \
    }

__global__ __launch_bounds__(256, 8) void k_gg_mid(int n,
                                                   const int* __restrict__ boundsG,
                                                   const int* __restrict__ csr,
                                                   const float* __restrict__ hs_in,
                                                   const float* __restrict__ dinv,
                                                   const float* __restrict__ w,
                                                   const float* __restrict__ b,
                                                   float* __restrict__ hs_out) {
    GATHER_CORE
    float breg = b[lane];
#pragma unroll 1
    for (int q = 0; q < RPW; ++q) {
        int v = v0 + q * 4 + r;
        if (v >= n) continue;
        float dv = dinv[v];
        rowl[r][lane] = acc[q] * dv;
        float o = breg;
#pragma unroll
        for (int k = 0; k < 64; ++k) o += rowl[r][k] * ws[k * 64 + lane];
        hs_out[(size_t)v * 64 + lane] = fmaxf(o, 0.f) * dv;
    }
}

__global__ __launch_bounds__(256, 8) void k_gg_final(int n,
                                                     const int* __restrict__ boundsG,
                                                     const int* __restrict__ csr,
                                                     const float* __restrict__ hs_in,
                                                     const float* __restrict__ dinv,
                                                     const float* __restrict__ w,
                                                     const float* __restrict__ b,
                                                     const float* __restrict__ fcw,
                                                     float* __restrict__ dots) {
    GATHER_CORE
    float breg = b[lane];
    float freg = fcw[lane];
#pragma unroll 1
    for (int q = 0; q < RPW; ++q) {
        int v = v0 + q * 4 + r;
        if (v >= n) continue;
        float dv = dinv[v];
        rowl[r][lane] = acc[q] * dv;
        float o = breg;
#pragma unroll
        for (int k = 0; k < 64; ++k) o += rowl[r][k] * ws[k * 64 + lane];
        float val = fmaxf(o, 0.f) * freg;
#pragma unroll
        for (int m = 32; m > 0; m >>= 1) val += __shfl_xor(val, m, 64);
        if (lane == 0) dots[v] = val;
    }
}

// pooled accumulation: LDS-binned segmented reduce over sorted batch
__global__ __launch_bounds__(256) void k_pool(int n, const float* __restrict__ dots,
                                              const int* __restrict__ batch,
                                              float* __restrict__ gsum,
                                              float* __restrict__ gcnt) {
    __shared__ float ls[64], lc[64];
    __shared__ int gmin_s;
    int tid = threadIdx.x;
    int i0 = blockIdx.x * 1024;
    if (tid == 0) gmin_s = batch[i0];
    if (tid < 64) { ls[tid] = 0.f; lc[tid] = 0.f; }
    __syncthreads();
    int gmin = gmin_s;
#pragma unroll
    for (int c = 0; c < 4; ++c) {
        int i = i0 + c * 256 + tid;
        if (i < n) {
            int g = batch[i];
            float d = dots[i];
            int rr = g - gmin;
            if (rr < 64) {
                atomicAdd(&ls[rr], d);
                atomicAdd(&lc[rr], 1.f);
            } else {
                atomicAdd(&gsum[g], d);
                atomicAdd(&gcnt[g], 1.f);
            }
        }
    }
    __syncthreads();
    if (tid < 64 && lc[tid] != 0.f) {
        atomicAdd(&gsum[gmin + tid], ls[tid]);
        atomicAdd(&gcnt[gmin + tid], lc[tid]);
    }
}

__global__ __launch_bounds__(256) void k_out(int g, const float* __restrict__ gsum,
                                             const float* __restrict__ gcnt,
                                             const float* __restrict__ fcb,
                                             float* __restrict__ out) {
    int i = blockIdx.x * blockDim.x + threadIdx.x;
    if (i < g) out[i] = gsum[i] / fmaxf(gcnt[i], 1.f) + fcb[0];
}

extern "C" void kernel_launch(void* const* d_in, const int* in_sizes, int n_in,
                              void* d_out, int out_size, void* d_ws, size_t ws_size,
                              hipStream_t stream) {
    const float* x    = (const float*)d_in[0];
    const int*   ei   = (const int*)d_in[1];
    const int*   batch= (const int*)d_in[2];
    const float* w1   = (const float*)d_in[3];
    const float* b1   = (const float*)d_in[4];
    const float* w2   = (const float*)d_in[5];
    const float* b2   = (const float*)d_in[6];
    const float* w3   = (const float*)d_in[7];
    const float* b3   = (const float*)d_in[8];
    const float* fcw  = (const float*)d_in[9];
    const float* fcb  = (const float*)d_in[10];
    float* out = (float*)d_out;

    const int N = in_sizes[0];           // needs N <= 131072 (17-bit packing)
    const int E = in_sizes[1] / 2;
    const int G = out_size;
    const int H = 64;
    const int nbkt = (N + SBS - 1) / SBS;        // 196 superblocks
    const int NBLK = (N + NB - 1) / NB;          // 3125 gather blocks
    const int NBLKP = nbkt * 16;                 // padded bounds rows

    const int* src = ei;
    const int* dst = ei + E;

    char* p = (char*)d_ws;
    int*   bucketCnt   = (int*)p; p += WS_ALIGN(sizeof(int) * BKTMAX);
    int*   bucketStart = (int*)p; p += WS_ALIGN(sizeof(int) * (BKTMAX + 1));
    int*   gCursor     = (int*)p; p += WS_ALIGN(sizeof(int) * BKTMAX);
    int*   pkbuf       = (int*)p; p += WS_ALIGN(sizeof(int) * (size_t)E);
    int*   csr         = (int*)p; p += WS_ALIGN(sizeof(int) * ((size_t)E + 4));
    int*   boundsG     = (int*)p; p += WS_ALIGN(sizeof(int) * (size_t)NBLKP * (NBIN + 1));
    float* dinv        = (float*)p; p += WS_ALIGN(sizeof(float) * N);
    float* xs          = (float*)p; p += WS_ALIGN(sizeof(float) * N);
    float* bufA        = (float*)p; p += WS_ALIGN(sizeof(float) * (size_t)N * H);
    float* bufB        = (float*)p; p += WS_ALIGN(sizeof(float) * (size_t)N * H);
    float* dots        = (float*)p; p += WS_ALIGN(sizeof(float) * N);
    float* gsum        = (float*)p; p += WS_ALIGN(sizeof(float) * G);
    float* gcnt        = (float*)p; p += WS_ALIGN(sizeof(float) * G);

    const int B = 256;
    int gridZ    = ((G > BKTMAX ? G : BKTMAX) + B - 1) / B;
    int gridT    = (E + P1T - 1) / P1T;
    int gridG    = (G + B - 1) / B;
    int gridPool = (N + 1023) / 1024;
    int gridPers = 2048;
    if (gridPers * 4 > N) gridPers = (N + 3) / 4;

    k_zero<<<gridZ, B, 0, stream>>>(G, E, bucketCnt, gCursor, csr, gsum, gcnt);
    k_cnt1<<<gridT, B, 0, stream>>>(E, dst, bucketCnt);
    k_scanB<<<1, B, 0, stream>>>(nbkt, E, bucketCnt, bucketStart);
    k_p1<<<gridT, B, 0, stream>>>(E, src, dst, bucketStart, gCursor, pkbuf);
    k_p2<<<nbkt, B, 0, stream>>>(N, bucketStart, pkbuf, x, csr, boundsG, dinv, xs);
    // layer 1 (rank-1, fused persistent)
    k_layer1<<<gridPers, B, 0, stream>>>(N, boundsG, csr, xs, dinv, w1, b1, bufA);
    // layer 2: fused gather + GEMM(w2) -> bufB
    k_gg_mid<<<NBLK, B, 0, stream>>>(N, boundsG, csr, bufA, dinv, w2, b2, bufB);
    // layer 3: fused gather + GEMM(w3) + fc dot -> dots
    k_gg_final<<<NBLK, B, 0, stream>>>(N, boundsG, csr, bufB, dinv, w3, b3, fcw, dots);
    // pooling + head
    k_pool<<<gridPool, B, 0, stream>>>(N, dots, batch, gsum, gcnt);
    k_out<<<gridG, B, 0, stream>>>(G, gsum, gcnt, fcb, out);
}

// Round 15
// 420.853 us; speedup vs baseline: 2.1992x; 1.1034x over previous
//
#include <hip/hip_runtime.h>
#include <hip/hip_bf16.h>

// GCN: 3x GCNConv(H=64) + global mean pool + linear head.
// Round 14 -> 15: whole-row gather. In the [row][chunk] CSR layout a row's
// 8 chunk segments are adjacent => process the row as ONE contiguous range
// (mean 32 edges, still chunk-sorted inside for the L2 sweep). Removes the
// chunk loop, 8x of the bounds reads, 8x of the tails, and all per-chunk
// barriers (they aligned nothing: blocks start staggered). 2-row pairing
// (R11-proven) retained. Build/p1/p2/layer1/pool unchanged from R14.

#define WS_ALIGN(x) (((x) + 255) & ~size_t(255))
#define NCHUNK 8
#define CSH 14           // chunk = src >> 14
#define NB 32            // dst rows per gather block
#define RPW (NB / 4)     // rows per wave = 8
#define NBIN (NB * NCHUNK)   // 256
#define USH 17
#define UMASK 0x1FFFF
#define BKTMAX 256
#define SBS 512
#define SBKEYS (SBS * NCHUNK)   // 4096
#define P1T 2048

__global__ __launch_bounds__(256) void k_zero(int g, int e, int* bucketCnt,
                                              int* gCursor, int* csr,
                                              float* gsum, float* gcnt) {
    int i = blockIdx.x * blockDim.x + threadIdx.x;
    if (i < BKTMAX) { bucketCnt[i] = 0; gCursor[i] = 0; }
    if (i < g) { gsum[i] = 0.f; gcnt[i] = 0.f; }
    if (i < 4) csr[e + i] = 0;
}

__global__ __launch_bounds__(256) void k_cnt1(int e, const int* __restrict__ dst,
                                              int* __restrict__ bucketCnt) {
    __shared__ int c[BKTMAX];
    int tid = threadIdx.x;
    c[tid] = 0;
    __syncthreads();
    int base = blockIdx.x * P1T;
#pragma unroll
    for (int q = 0; q < P1T / 256; ++q) {
        int i = base + q * 256 + tid;
        if (i < e) atomicAdd(&c[dst[i] >> 9], 1);
    }
    __syncthreads();
    if (c[tid] > 0) atomicAdd(&bucketCnt[tid], c[tid]);
}

__global__ __launch_bounds__(256) void k_scanB(int nbkt, int e,
                                               const int* __restrict__ bucketCnt,
                                               int* __restrict__ bucketStart) {
    __shared__ int sd[256];
    int tid = threadIdx.x;
    int v = (tid < nbkt) ? bucketCnt[tid] : 0;
    sd[tid] = v;
    __syncthreads();
    for (int off = 1; off < 256; off <<= 1) {
        int t = (tid >= off) ? sd[tid - off] : 0;
        __syncthreads();
        sd[tid] += t;
        __syncthreads();
    }
    if (tid < nbkt) bucketStart[tid] = sd[tid] - v;
    if (tid == 0) bucketStart[nbkt] = e;
}

// p1: tile sort by superblock, contiguous run writes of packed words
__global__ __launch_bounds__(256) void k_p1(int e, const int* __restrict__ src,
                                            const int* __restrict__ dst,
                                            const int* __restrict__ bucketStart,
                                            int* __restrict__ gCursor,
                                            int* __restrict__ pkbuf) {
    __shared__ int cnt[BKTMAX], exc[BKTMAX], cur[BKTMAX], bb[BKTMAX];
    __shared__ int sd[256];
    __shared__ int stage[P1T];
    __shared__ unsigned char stgb[P1T];
    int tid = threadIdx.x;
    cnt[tid] = 0;
    __syncthreads();
    int base = blockIdx.x * P1T;
    int m = e - base; if (m > P1T) m = P1T;
    int pk8[P1T / 256];
    int b8[P1T / 256];
#pragma unroll
    for (int q = 0; q < P1T / 256; ++q) {
        int li = q * 256 + tid;
        if (li < m) {
            int d = dst[base + li];
            int s = src[base + li];
            int b = d >> 9;
            b8[q] = b;
            pk8[q] = ((d & (SBS - 1)) << USH) | s;
            atomicAdd(&cnt[b], 1);
        }
    }
    __syncthreads();
    int cv = cnt[tid];
    sd[tid] = cv;
    __syncthreads();
    for (int off = 1; off < 256; off <<= 1) {
        int t = (tid >= off) ? sd[tid - off] : 0;
        __syncthreads();
        sd[tid] += t;
        __syncthreads();
    }
    exc[tid] = sd[tid] - cv;
    cur[tid] = sd[tid] - cv;
    if (cv > 0) bb[tid] = atomicAdd(&gCursor[tid], cv);
    __syncthreads();
#pragma unroll
    for (int q = 0; q < P1T / 256; ++q) {
        int li = q * 256 + tid;
        if (li < m) {
            int b = b8[q];
            int pos = atomicAdd(&cur[b], 1);
            stage[pos] = pk8[q];
            stgb[pos] = (unsigned char)b;
        }
    }
    __syncthreads();
#pragma unroll
    for (int q = 0; q < P1T / 256; ++q) {
        int p = q * 256 + tid;
        if (p < m) {
            int b = stgb[p];
            pkbuf[bucketStart[b] + bb[b] + (p - exc[b])] = stage[p];
        }
    }
}

// p2: per-superblock counting sort -> csr [row][chunk] + bounds + dinv/xs
__global__ __launch_bounds__(256) void k_p2(int n, const int* __restrict__ bucketStart,
                                            const int* __restrict__ pkbuf,
                                            const float* __restrict__ x,
                                            int* __restrict__ csr,
                                            int* __restrict__ boundsG,
                                            float* __restrict__ dinv,
                                            float* __restrict__ xs) {
    __shared__ int cnt[SBKEYS + 1];
    __shared__ int sd[256];
    int sb = blockIdx.x, tid = threadIdx.x;
    int r0 = bucketStart[sb], r1 = bucketStart[sb + 1];
    for (int k = tid; k < SBKEYS + 1; k += 256) cnt[k] = 0;
    __syncthreads();
    for (int i = r0 + tid; i < r1; i += 256) {
        int w = pkbuf[i];
        int key = ((w >> USH) << 3) | ((w & UMASK) >> CSH);
        atomicAdd(&cnt[key], 1);
    }
    __syncthreads();
    int base16 = tid * 16;
    int loc[16]; int s = 0;
#pragma unroll
    for (int j = 0; j < 16; ++j) { loc[j] = cnt[base16 + j]; s += loc[j]; }
    sd[tid] = s;
    __syncthreads();
    for (int off = 1; off < 256; off <<= 1) {
        int t = (tid >= off) ? sd[tid - off] : 0;
        __syncthreads();
        sd[tid] += t;
        __syncthreads();
    }
    int run = sd[tid] - s;
#pragma unroll
    for (int j = 0; j < 16; ++j) { cnt[base16 + j] = run; run += loc[j]; }
    if (tid == 255) cnt[SBKEYS] = run;
    __syncthreads();
    for (int k = tid; k < SBKEYS; k += 256) {
        int bi = sb * 16 + (k >> 8);
        boundsG[(size_t)bi * (NBIN + 1) + (k & 255)] = r0 + cnt[k];
    }
    if (tid < 16)
        boundsG[(size_t)(sb * 16 + tid) * (NBIN + 1) + NBIN] = r0 + cnt[(tid + 1) * 256];
    for (int dl = tid; dl < SBS; dl += 256) {
        int v = sb * SBS + dl;
        if (v < n) {
            int deg = cnt[dl * 8 + 8] - cnt[dl * 8] + 1;
            float di = 1.0f / sqrtf((float)deg);
            dinv[v] = di;
            xs[v] = x[v] * di;
        }
    }
    __syncthreads();
    for (int i = r0 + tid; i < r1; i += 256) {
        int w = pkbuf[i];
        int srcv = w & UMASK;
        int key = ((w >> USH) << 3) | (srcv >> CSH);
        int pos = atomicAdd(&cnt[key], 1);
        csr[r0 + pos] = srcv;
    }
}

// layer 1 fused (rank-1), persistent wave-per-node
__global__ __launch_bounds__(256, 8) void k_layer1(int n, const int* __restrict__ boundsG,
                                                   const int* __restrict__ csr,
                                                   const float* __restrict__ xs,
                                                   const float* __restrict__ dinv,
                                                   const float* __restrict__ w1,
                                                   const float* __restrict__ b1,
                                                   float* __restrict__ hs_out) {
    int tid = threadIdx.x;
    int r = tid >> 6, lane = tid & 63;
    float w1r = w1[lane], b1r = b1[lane];
    int wid = blockIdx.x * 4 + r;
    int stride = gridDim.x * 4;
    for (int v = wid; v < n; v += stride) {
        int bi = v / NB, vi = v & (NB - 1);
        size_t base = (size_t)bi * (NBIN + 1) + vi * NCHUNK;
        int s0 = boundsG[base], s1 = boundsG[base + NCHUNK];
        float acc = 0.f;
        for (int k = s0 + lane; k < s1; k += 64) acc += xs[csr[k]];
#pragma unroll
        for (int m = 32; m > 0; m >>= 1) acc += __shfl_xor(acc, m, 64);
        float dv = dinv[v];
        float s = (acc + xs[v]) * dv;
        hs_out[(size_t)v * 64 + lane] = fmaxf(s * w1r + b1r, 0.f) * dv;
    }
}

// ---- fused whole-row gather + inline GEMM ----
// Row's edges are contiguous (chunk-sorted inside). 2-row pairing, quad loads.
// No chunk loop, no per-chunk barriers.
#define GATHER_CORE                                                            \
    __shared__ float ws[64 * 64];                                              \
    __shared__ float rowl[4][64];                                              \
    __shared__ int bndL[NBIN + 1];                                             \
    int tid = threadIdx.x;                                                     \
    int lane = tid & 63;                                                       \
    int r = tid >> 6;                                                          \
    int v0 = blockIdx.x * NB;                                                  \
    for (int k = tid; k < 64 * 64; k += 256) ws[k] = w[k];                     \
    for (int i = tid; i < NBIN + 1; i += 256)                                  \
        bndL[i] = boundsG[(size_t)blockIdx.x * (NBIN + 1) + i];                \
    float acc[RPW];                                                            \
    _Pragma("unroll")                                                          \
    for (int q = 0; q < RPW; ++q) {                                            \
        int v = v0 + q * 4 + r;                                                \
        acc[q] = (v < n) ? hs_in[(size_t)v * 64 + lane] : 0.f;                 \
    }                                                                          \
    __syncthreads();                                                           \
    _Pragma("unroll")                                                          \
    for (int t = 0; t < RPW / 2; ++t) {                                        \
        int viA = (2 * t) * 4 + r;                                             \
        int viB = (2 * t + 1) * 4 + r;                                         \
        int a0 = __builtin_amdgcn_readfirstlane(bndL[viA * NCHUNK]);           \
        int a1 = __builtin_amdgcn_readfirstlane(bndL[viA * NCHUNK + NCHUNK]);  \
        int b0_ = __builtin_amdgcn_readfirstlane(bndL[viB * NCHUNK]);          \
        int b1_ = __builtin_amdgcn_readfirstlane(bndL[viB * NCHUNK + NCHUNK]); \
        int ba = a0, bb = b0_;                                                 \
        while (ba < a1 || bb < b1_) {                                          \
            int remA = a1 - ba;                                                \
            int remB = b1_ - bb;                                               \
            int pa = (remA > 0) ? ba : bb;                                     \
            int pb = (remB > 0) ? bb : ba;                                     \
            int uA0 = csr[pa],     uA1 = csr[pa + 1];                          \
            int uA2 = csr[pa + 2], uA3 = csr[pa + 3];                          \
            int uB0 = csr[pb],     uB1 = csr[pb + 1];                          \
            int uB2 = csr[pb + 2], uB3 = csr[pb + 3];                          \
            float gA0 = hs_in[(size_t)uA0 * 64 + lane];                        \
            float gA1 = hs_in[(size_t)uA1 * 64 + lane];                        \
            float gA2 = hs_in[(size_t)uA2 * 64 + lane];                        \
            float gA3 = hs_in[(size_t)uA3 * 64 + lane];                        \
            float gB0 = hs_in[(size_t)uB0 * 64 + lane];                        \
            float gB1 = hs_in[(size_t)uB1 * 64 + lane];                        \
            float gB2 = hs_in[(size_t)uB2 * 64 + lane];                        \
            float gB3 = hs_in[(size_t)uB3 * 64 + lane];                        \
            if (remA >= 4) acc[2 * t] += (gA0 + gA1) + (gA2 + gA3);            \
            else if (remA > 0) {                                               \
                acc[2 * t] += gA0;                                             \
                if (remA > 1) acc[2 * t] += gA1;                               \
                if (remA > 2) acc[2 * t] += gA2;                               \
            }                                                                  \
            if (remB >= 4) acc[2 * t + 1] += (gB0 + gB1) + (gB2 + gB3);        \
            else if (remB > 0) {                                               \
                acc[2 * t + 1] += gB0;                                         \
                if (remB > 1) acc[2 * t + 1] += gB1;                           \
                if (remB > 2) acc[2 * t + 1] += gB2;                           \
            }                                                                  \
            ba += 4; bb += 4;                                                  \
        }                                                                      \
    }

__global__ __launch_bounds__(256, 8) void k_gg_mid(int n,
                                                   const int* __restrict__ boundsG,
                                                   const int* __restrict__ csr,
                                                   const float* __restrict__ hs_in,
                                                   const float* __restrict__ dinv,
                                                   const float* __restrict__ w,
                                                   const float* __restrict__ b,
                                                   float* __restrict__ hs_out) {
    GATHER_CORE
    float breg = b[lane];
#pragma unroll 1
    for (int q = 0; q < RPW; ++q) {
        int v = v0 + q * 4 + r;
        if (v >= n) continue;
        float dv = dinv[v];
        rowl[r][lane] = acc[q] * dv;
        float o = breg;
#pragma unroll
        for (int k = 0; k < 64; ++k) o += rowl[r][k] * ws[k * 64 + lane];
        hs_out[(size_t)v * 64 + lane] = fmaxf(o, 0.f) * dv;
    }
}

__global__ __launch_bounds__(256, 8) void k_gg_final(int n,
                                                     const int* __restrict__ boundsG,
                                                     const int* __restrict__ csr,
                                                     const float* __restrict__ hs_in,
                                                     const float* __restrict__ dinv,
                                                     const float* __restrict__ w,
                                                     const float* __restrict__ b,
                                                     const float* __restrict__ fcw,
                                                     float* __restrict__ dots) {
    GATHER_CORE
    float breg = b[lane];
    float freg = fcw[lane];
#pragma unroll 1
    for (int q = 0; q < RPW; ++q) {
        int v = v0 + q * 4 + r;
        if (v >= n) continue;
        float dv = dinv[v];
        rowl[r][lane] = acc[q] * dv;
        float o = breg;
#pragma unroll
        for (int k = 0; k < 64; ++k) o += rowl[r][k] * ws[k * 64 + lane];
        float val = fmaxf(o, 0.f) * freg;
#pragma unroll
        for (int m = 32; m > 0; m >>= 1) val += __shfl_xor(val, m, 64);
        if (lane == 0) dots[v] = val;
    }
}

// pooled accumulation: LDS-binned segmented reduce over sorted batch
__global__ __launch_bounds__(256) void k_pool(int n, const float* __restrict__ dots,
                                              const int* __restrict__ batch,
                                              float* __restrict__ gsum,
                                              float* __restrict__ gcnt) {
    __shared__ float ls[64], lc[64];
    __shared__ int gmin_s;
    int tid = threadIdx.x;
    int i0 = blockIdx.x * 1024;
    if (tid == 0) gmin_s = batch[i0];
    if (tid < 64) { ls[tid] = 0.f; lc[tid] = 0.f; }
    __syncthreads();
    int gmin = gmin_s;
#pragma unroll
    for (int c = 0; c < 4; ++c) {
        int i = i0 + c * 256 + tid;
        if (i < n) {
            int g = batch[i];
            float d = dots[i];
            int rr = g - gmin;
            if (rr < 64) {
                atomicAdd(&ls[rr], d);
                atomicAdd(&lc[rr], 1.f);
            } else {
                atomicAdd(&gsum[g], d);
                atomicAdd(&gcnt[g], 1.f);
            }
        }
    }
    __syncthreads();
    if (tid < 64 && lc[tid] != 0.f) {
        atomicAdd(&gsum[gmin + tid], ls[tid]);
        atomicAdd(&gcnt[gmin + tid], lc[tid]);
    }
}

__global__ __launch_bounds__(256) void k_out(int g, const float* __restrict__ gsum,
                                             const float* __restrict__ gcnt,
                                             const float* __restrict__ fcb,
                                             float* __restrict__ out) {
    int i = blockIdx.x * blockDim.x + threadIdx.x;
    if (i < g) out[i] = gsum[i] / fmaxf(gcnt[i], 1.f) + fcb[0];
}

extern "C" void kernel_launch(void* const* d_in, const int* in_sizes, int n_in,
                              void* d_out, int out_size, void* d_ws, size_t ws_size,
                              hipStream_t stream) {
    const float* x    = (const float*)d_in[0];
    const int*   ei   = (const int*)d_in[1];
    const int*   batch= (const int*)d_in[2];
    const float* w1   = (const float*)d_in[3];
    const float* b1   = (const float*)d_in[4];
    const float* w2   = (const float*)d_in[5];
    const float* b2   = (const float*)d_in[6];
    const float* w3   = (const float*)d_in[7];
    const float* b3   = (const float*)d_in[8];
    const float* fcw  = (const float*)d_in[9];
    const float* fcb  = (const float*)d_in[10];
    float* out = (float*)d_out;

    const int N = in_sizes[0];           // needs N <= 131072 (17-bit packing)
    const int E = in_sizes[1] / 2;
    const int G = out_size;
    const int H = 64;
    const int nbkt = (N + SBS - 1) / SBS;        // 196 superblocks
    const int NBLK = (N + NB - 1) / NB;          // 3125 gather blocks
    const int NBLKP = nbkt * 16;                 // padded bounds rows

    const int* src = ei;
    const int* dst = ei + E;

    char* p = (char*)d_ws;
    int*   bucketCnt   = (int*)p; p += WS_ALIGN(sizeof(int) * BKTMAX);
    int*   bucketStart = (int*)p; p += WS_ALIGN(sizeof(int) * (BKTMAX + 1));
    int*   gCursor     = (int*)p; p += WS_ALIGN(sizeof(int) * BKTMAX);
    int*   pkbuf       = (int*)p; p += WS_ALIGN(sizeof(int) * (size_t)E);
    int*   csr         = (int*)p; p += WS_ALIGN(sizeof(int) * ((size_t)E + 4));
    int*   boundsG     = (int*)p; p += WS_ALIGN(sizeof(int) * (size_t)NBLKP * (NBIN + 1));
    float* dinv        = (float*)p; p += WS_ALIGN(sizeof(float) * N);
    float* xs          = (float*)p; p += WS_ALIGN(sizeof(float) * N);
    float* bufA        = (float*)p; p += WS_ALIGN(sizeof(float) * (size_t)N * H);
    float* bufB        = (float*)p; p += WS_ALIGN(sizeof(float) * (size_t)N * H);
    float* dots        = (float*)p; p += WS_ALIGN(sizeof(float) * N);
    float* gsum        = (float*)p; p += WS_ALIGN(sizeof(float) * G);
    float* gcnt        = (float*)p; p += WS_ALIGN(sizeof(float) * G);

    const int B = 256;
    int gridZ    = ((G > BKTMAX ? G : BKTMAX) + B - 1) / B;
    int gridT    = (E + P1T - 1) / P1T;
    int gridG    = (G + B - 1) / B;
    int gridPool = (N + 1023) / 1024;
    int gridPers = 2048;
    if (gridPers * 4 > N) gridPers = (N + 3) / 4;

    k_zero<<<gridZ, B, 0, stream>>>(G, E, bucketCnt, gCursor, csr, gsum, gcnt);
    k_cnt1<<<gridT, B, 0, stream>>>(E, dst, bucketCnt);
    k_scanB<<<1, B, 0, stream>>>(nbkt, E, bucketCnt, bucketStart);
    k_p1<<<gridT, B, 0, stream>>>(E, src, dst, bucketStart, gCursor, pkbuf);
    k_p2<<<nbkt, B, 0, stream>>>(N, bucketStart, pkbuf, x, csr, boundsG, dinv, xs);
    // layer 1 (rank-1, fused persistent)
    k_layer1<<<gridPers, B, 0, stream>>>(N, boundsG, csr, xs, dinv, w1, b1, bufA);
    // layer 2: fused gather + GEMM(w2) -> bufB
    k_gg_mid<<<NBLK, B, 0, stream>>>(N, boundsG, csr, bufA, dinv, w2, b2, bufB);
    // layer 3: fused gather + GEMM(w3) + fc dot -> dots
    k_gg_final<<<NBLK, B, 0, stream>>>(N, boundsG, csr, bufB, dinv, w3, b3, fcw, dots);
    // pooling + head
    k_pool<<<gridPool, B, 0, stream>>>(N, dots, batch, gsum, gcnt);
    k_out<<<gridG, B, 0, stream>>>(G, gsum, gcnt, fcb, out);
}

// Round 16
// 387.837 us; speedup vs baseline: 2.3864x; 1.0851x over previous
//
#include <hip/hip_runtime.h>
#include <hip/hip_bf16.h>

// GCN: 3x GCNConv(H=64) + global mean pool + linear head.
// Round 15 -> 16: bf16 feature buffers. hs1/hs2 stored as bf16 (RNE), all
// accumulation in f32, weights f32. Per-edge row read 256B -> 128B; halves
// the gather kernels' L2-miss traffic (373MB -> ~220MB) which R15 showed is
// the limiter. Error analysis: positive gather sums + mean-pool attenuate
// bf16's 0.2% per-value error to ~2e-6 at the output (threshold 1.19e-5).
// Everything else identical to R15 (whole-row gather, p1/p2 build).

#define WS_ALIGN(x) (((x) + 255) & ~size_t(255))
#define NCHUNK 8
#define CSH 14           // chunk = src >> 14
#define NB 32            // dst rows per gather block
#define RPW (NB / 4)     // rows per wave = 8
#define NBIN (NB * NCHUNK)   // 256
#define USH 17
#define UMASK 0x1FFFF
#define BKTMAX 256
#define SBS 512
#define SBKEYS (SBS * NCHUNK)   // 4096
#define P1T 2048

__device__ __forceinline__ float bf2f(unsigned short h) {
    union { unsigned u; float f; } t;
    t.u = ((unsigned)h) << 16;
    return t.f;
}
__device__ __forceinline__ unsigned short f2bf(float f) {
    union { float f; unsigned u; } t;
    t.f = f;
    unsigned r = t.u + 0x7FFF + ((t.u >> 16) & 1);   // round-to-nearest-even
    return (unsigned short)(r >> 16);
}

__global__ __launch_bounds__(256) void k_zero(int g, int e, int* bucketCnt,
                                              int* gCursor, int* csr,
                                              float* gsum, float* gcnt) {
    int i = blockIdx.x * blockDim.x + threadIdx.x;
    if (i < BKTMAX) { bucketCnt[i] = 0; gCursor[i] = 0; }
    if (i < g) { gsum[i] = 0.f; gcnt[i] = 0.f; }
    if (i < 4) csr[e + i] = 0;
}

__global__ __launch_bounds__(256) void k_cnt1(int e, const int* __restrict__ dst,
                                              int* __restrict__ bucketCnt) {
    __shared__ int c[BKTMAX];
    int tid = threadIdx.x;
    c[tid] = 0;
    __syncthreads();
    int base = blockIdx.x * P1T;
#pragma unroll
    for (int q = 0; q < P1T / 256; ++q) {
        int i = base + q * 256 + tid;
        if (i < e) atomicAdd(&c[dst[i] >> 9], 1);
    }
    __syncthreads();
    if (c[tid] > 0) atomicAdd(&bucketCnt[tid], c[tid]);
}

__global__ __launch_bounds__(256) void k_scanB(int nbkt, int e,
                                               const int* __restrict__ bucketCnt,
                                               int* __restrict__ bucketStart) {
    __shared__ int sd[256];
    int tid = threadIdx.x;
    int v = (tid < nbkt) ? bucketCnt[tid] : 0;
    sd[tid] = v;
    __syncthreads();
    for (int off = 1; off < 256; off <<= 1) {
        int t = (tid >= off) ? sd[tid - off] : 0;
        __syncthreads();
        sd[tid] += t;
        __syncthreads();
    }
    if (tid < nbkt) bucketStart[tid] = sd[tid] - v;
    if (tid == 0) bucketStart[nbkt] = e;
}

// p1: tile sort by superblock, contiguous run writes of packed words
__global__ __launch_bounds__(256) void k_p1(int e, const int* __restrict__ src,
                                            const int* __restrict__ dst,
                                            const int* __restrict__ bucketStart,
                                            int* __restrict__ gCursor,
                                            int* __restrict__ pkbuf) {
    __shared__ int cnt[BKTMAX], exc[BKTMAX], cur[BKTMAX], bb[BKTMAX];
    __shared__ int sd[256];
    __shared__ int stage[P1T];
    __shared__ unsigned char stgb[P1T];
    int tid = threadIdx.x;
    cnt[tid] = 0;
    __syncthreads();
    int base = blockIdx.x * P1T;
    int m = e - base; if (m > P1T) m = P1T;
    int pk8[P1T / 256];
    int b8[P1T / 256];
#pragma unroll
    for (int q = 0; q < P1T / 256; ++q) {
        int li = q * 256 + tid;
        if (li < m) {
            int d = dst[base + li];
            int s = src[base + li];
            int b = d >> 9;
            b8[q] = b;
            pk8[q] = ((d & (SBS - 1)) << USH) | s;
            atomicAdd(&cnt[b], 1);
        }
    }
    __syncthreads();
    int cv = cnt[tid];
    sd[tid] = cv;
    __syncthreads();
    for (int off = 1; off < 256; off <<= 1) {
        int t = (tid >= off) ? sd[tid - off] : 0;
        __syncthreads();
        sd[tid] += t;
        __syncthreads();
    }
    exc[tid] = sd[tid] - cv;
    cur[tid] = sd[tid] - cv;
    if (cv > 0) bb[tid] = atomicAdd(&gCursor[tid], cv);
    __syncthreads();
#pragma unroll
    for (int q = 0; q < P1T / 256; ++q) {
        int li = q * 256 + tid;
        if (li < m) {
            int b = b8[q];
            int pos = atomicAdd(&cur[b], 1);
            stage[pos] = pk8[q];
            stgb[pos] = (unsigned char)b;
        }
    }
    __syncthreads();
#pragma unroll
    for (int q = 0; q < P1T / 256; ++q) {
        int p = q * 256 + tid;
        if (p < m) {
            int b = stgb[p];
            pkbuf[bucketStart[b] + bb[b] + (p - exc[b])] = stage[p];
        }
    }
}

// p2: per-superblock counting sort -> csr [row][chunk] + bounds + dinv/xs
__global__ __launch_bounds__(256) void k_p2(int n, const int* __restrict__ bucketStart,
                                            const int* __restrict__ pkbuf,
                                            const float* __restrict__ x,
                                            int* __restrict__ csr,
                                            int* __restrict__ boundsG,
                                            float* __restrict__ dinv,
                                            float* __restrict__ xs) {
    __shared__ int cnt[SBKEYS + 1];
    __shared__ int sd[256];
    int sb = blockIdx.x, tid = threadIdx.x;
    int r0 = bucketStart[sb], r1 = bucketStart[sb + 1];
    for (int k = tid; k < SBKEYS + 1; k += 256) cnt[k] = 0;
    __syncthreads();
    for (int i = r0 + tid; i < r1; i += 256) {
        int w = pkbuf[i];
        int key = ((w >> USH) << 3) | ((w & UMASK) >> CSH);
        atomicAdd(&cnt[key], 1);
    }
    __syncthreads();
    int base16 = tid * 16;
    int loc[16]; int s = 0;
#pragma unroll
    for (int j = 0; j < 16; ++j) { loc[j] = cnt[base16 + j]; s += loc[j]; }
    sd[tid] = s;
    __syncthreads();
    for (int off = 1; off < 256; off <<= 1) {
        int t = (tid >= off) ? sd[tid - off] : 0;
        __syncthreads();
        sd[tid] += t;
        __syncthreads();
    }
    int run = sd[tid] - s;
#pragma unroll
    for (int j = 0; j < 16; ++j) { cnt[base16 + j] = run; run += loc[j]; }
    if (tid == 255) cnt[SBKEYS] = run;
    __syncthreads();
    for (int k = tid; k < SBKEYS; k += 256) {
        int bi = sb * 16 + (k >> 8);
        boundsG[(size_t)bi * (NBIN + 1) + (k & 255)] = r0 + cnt[k];
    }
    if (tid < 16)
        boundsG[(size_t)(sb * 16 + tid) * (NBIN + 1) + NBIN] = r0 + cnt[(tid + 1) * 256];
    for (int dl = tid; dl < SBS; dl += 256) {
        int v = sb * SBS + dl;
        if (v < n) {
            int deg = cnt[dl * 8 + 8] - cnt[dl * 8] + 1;
            float di = 1.0f / sqrtf((float)deg);
            dinv[v] = di;
            xs[v] = x[v] * di;
        }
    }
    __syncthreads();
    for (int i = r0 + tid; i < r1; i += 256) {
        int w = pkbuf[i];
        int srcv = w & UMASK;
        int key = ((w >> USH) << 3) | (srcv >> CSH);
        int pos = atomicAdd(&cnt[key], 1);
        csr[r0 + pos] = srcv;
    }
}

// layer 1 fused (rank-1), persistent wave-per-node; bf16 output
__global__ __launch_bounds__(256, 8) void k_layer1(int n, const int* __restrict__ boundsG,
                                                   const int* __restrict__ csr,
                                                   const float* __restrict__ xs,
                                                   const float* __restrict__ dinv,
                                                   const float* __restrict__ w1,
                                                   const float* __restrict__ b1,
                                                   unsigned short* __restrict__ hs_out) {
    int tid = threadIdx.x;
    int r = tid >> 6, lane = tid & 63;
    float w1r = w1[lane], b1r = b1[lane];
    int wid = blockIdx.x * 4 + r;
    int stride = gridDim.x * 4;
    for (int v = wid; v < n; v += stride) {
        int bi = v / NB, vi = v & (NB - 1);
        size_t base = (size_t)bi * (NBIN + 1) + vi * NCHUNK;
        int s0 = boundsG[base], s1 = boundsG[base + NCHUNK];
        float acc = 0.f;
        for (int k = s0 + lane; k < s1; k += 64) acc += xs[csr[k]];
#pragma unroll
        for (int m = 32; m > 0; m >>= 1) acc += __shfl_xor(acc, m, 64);
        float dv = dinv[v];
        float s = (acc + xs[v]) * dv;
        hs_out[(size_t)v * 64 + lane] = f2bf(fmaxf(s * w1r + b1r, 0.f) * dv);
    }
}

// ---- fused whole-row gather (bf16 in) + inline GEMM (f32) ----
#define GATHER_CORE                                                            \
    __shared__ float ws[64 * 64];                                              \
    __shared__ float rowl[4][64];                                              \
    __shared__ int bndL[NBIN + 1];                                             \
    int tid = threadIdx.x;                                                     \
    int lane = tid & 63;                                                       \
    int r = tid >> 6;                                                          \
    int v0 = blockIdx.x * NB;                                                  \
    for (int k = tid; k < 64 * 64; k += 256) ws[k] = w[k];                     \
    for (int i = tid; i < NBIN + 1; i += 256)                                  \
        bndL[i] = boundsG[(size_t)blockIdx.x * (NBIN + 1) + i];                \
    float acc[RPW];                                                            \
    _Pragma("unroll")                                                          \
    for (int q = 0; q < RPW; ++q) {                                            \
        int v = v0 + q * 4 + r;                                                \
        acc[q] = (v < n) ? bf2f(hs_in[(size_t)v * 64 + lane]) : 0.f;           \
    }                                                                          \
    __syncthreads();                                                           \
    _Pragma("unroll")                                                          \
    for (int t = 0; t < RPW / 2; ++t) {                                        \
        int viA = (2 * t) * 4 + r;                                             \
        int viB = (2 * t + 1) * 4 + r;                                         \
        int a0 = __builtin_amdgcn_readfirstlane(bndL[viA * NCHUNK]);           \
        int a1 = __builtin_amdgcn_readfirstlane(bndL[viA * NCHUNK + NCHUNK]);  \
        int b0_ = __builtin_amdgcn_readfirstlane(bndL[viB * NCHUNK]);          \
        int b1_ = __builtin_amdgcn_readfirstlane(bndL[viB * NCHUNK + NCHUNK]); \
        int ba = a0, bb = b0_;                                                 \
        while (ba < a1 || bb < b1_) {                                          \
            int remA = a1 - ba;                                                \
            int remB = b1_ - bb;                                               \
            int pa = (remA > 0) ? ba : bb;                                     \
            int pb = (remB > 0) ? bb : ba;                                     \
            int uA0 = csr[pa],     uA1 = csr[pa + 1];                          \
            int uA2 = csr[pa + 2], uA3 = csr[pa + 3];                          \
            int uB0 = csr[pb],     uB1 = csr[pb + 1];                          \
            int uB2 = csr[pb + 2], uB3 = csr[pb + 3];                          \
            float gA0 = bf2f(hs_in[(size_t)uA0 * 64 + lane]);                  \
            float gA1 = bf2f(hs_in[(size_t)uA1 * 64 + lane]);                  \
            float gA2 = bf2f(hs_in[(size_t)uA2 * 64 + lane]);                  \
            float gA3 = bf2f(hs_in[(size_t)uA3 * 64 + lane]);                  \
            float gB0 = bf2f(hs_in[(size_t)uB0 * 64 + lane]);                  \
            float gB1 = bf2f(hs_in[(size_t)uB1 * 64 + lane]);                  \
            float gB2 = bf2f(hs_in[(size_t)uB2 * 64 + lane]);                  \
            float gB3 = bf2f(hs_in[(size_t)uB3 * 64 + lane]);                  \
            if (remA >= 4) acc[2 * t] += (gA0 + gA1) + (gA2 + gA3);            \
            else if (remA > 0) {                                               \
                acc[2 * t] += gA0;                                             \
                if (remA > 1) acc[2 * t] += gA1;                               \
                if (remA > 2) acc[2 * t] += gA2;                               \
            }                                                                  \
            if (remB >= 4) acc[2 * t + 1] += (gB0 + gB1) + (gB2 + gB3);        \
            else if (remB > 0) {                                               \
                acc[2 * t + 1] += gB0;                                         \
                if (remB > 1) acc[2 * t + 1] += gB1;                           \
                if (remB > 2) acc[2 * t + 1] += gB2;                           \
            }                                                                  \
            ba += 4; bb += 4;                                                  \
        }                                                                      \
    }

__global__ __launch_bounds__(256, 8) void k_gg_mid(int n,
                                                   const int* __restrict__ boundsG,
                                                   const int* __restrict__ csr,
                                                   const unsigned short* __restrict__ hs_in,
                                                   const float* __restrict__ dinv,
                                                   const float* __restrict__ w,
                                                   const float* __restrict__ b,
                                                   unsigned short* __restrict__ hs_out) {
    GATHER_CORE
    float breg = b[lane];
#pragma unroll 1
    for (int q = 0; q < RPW; ++q) {
        int v = v0 + q * 4 + r;
        if (v >= n) continue;
        float dv = dinv[v];
        rowl[r][lane] = acc[q] * dv;
        float o = breg;
#pragma unroll
        for (int k = 0; k < 64; ++k) o += rowl[r][k] * ws[k * 64 + lane];
        hs_out[(size_t)v * 64 + lane] = f2bf(fmaxf(o, 0.f) * dv);
    }
}

__global__ __launch_bounds__(256, 8) void k_gg_final(int n,
                                                     const int* __restrict__ boundsG,
                                                     const int* __restrict__ csr,
                                                     const unsigned short* __restrict__ hs_in,
                                                     const float* __restrict__ dinv,
                                                     const float* __restrict__ w,
                                                     const float* __restrict__ b,
                                                     const float* __restrict__ fcw,
                                                     float* __restrict__ dots) {
    GATHER_CORE
    float breg = b[lane];
    float freg = fcw[lane];
#pragma unroll 1
    for (int q = 0; q < RPW; ++q) {
        int v = v0 + q * 4 + r;
        if (v >= n) continue;
        float dv = dinv[v];
        rowl[r][lane] = acc[q] * dv;
        float o = breg;
#pragma unroll
        for (int k = 0; k < 64; ++k) o += rowl[r][k] * ws[k * 64 + lane];
        float val = fmaxf(o, 0.f) * freg;
#pragma unroll
        for (int m = 32; m > 0; m >>= 1) val += __shfl_xor(val, m, 64);
        if (lane == 0) dots[v] = val;
    }
}

// pooled accumulation: LDS-binned segmented reduce over sorted batch
__global__ __launch_bounds__(256) void k_pool(int n, const float* __restrict__ dots,
                                              const int* __restrict__ batch,
                                              float* __restrict__ gsum,
                                              float* __restrict__ gcnt) {
    __shared__ float ls[64], lc[64];
    __shared__ int gmin_s;
    int tid = threadIdx.x;
    int i0 = blockIdx.x * 1024;
    if (tid == 0) gmin_s = batch[i0];
    if (tid < 64) { ls[tid] = 0.f; lc[tid] = 0.f; }
    __syncthreads();
    int gmin = gmin_s;
#pragma unroll
    for (int c = 0; c < 4; ++c) {
        int i = i0 + c * 256 + tid;
        if (i < n) {
            int g = batch[i];
            float d = dots[i];
            int rr = g - gmin;
            if (rr < 64) {
                atomicAdd(&ls[rr], d);
                atomicAdd(&lc[rr], 1.f);
            } else {
                atomicAdd(&gsum[g], d);
                atomicAdd(&gcnt[g], 1.f);
            }
        }
    }
    __syncthreads();
    if (tid < 64 && lc[tid] != 0.f) {
        atomicAdd(&gsum[gmin + tid], ls[tid]);
        atomicAdd(&gcnt[gmin + tid], lc[tid]);
    }
}

__global__ __launch_bounds__(256) void k_out(int g, const float* __restrict__ gsum,
                                             const float* __restrict__ gcnt,
                                             const float* __restrict__ fcb,
                                             float* __restrict__ out) {
    int i = blockIdx.x * blockDim.x + threadIdx.x;
    if (i < g) out[i] = gsum[i] / fmaxf(gcnt[i], 1.f) + fcb[0];
}

extern "C" void kernel_launch(void* const* d_in, const int* in_sizes, int n_in,
                              void* d_out, int out_size, void* d_ws, size_t ws_size,
                              hipStream_t stream) {
    const float* x    = (const float*)d_in[0];
    const int*   ei   = (const int*)d_in[1];
    const int*   batch= (const int*)d_in[2];
    const float* w1   = (const float*)d_in[3];
    const float* b1   = (const float*)d_in[4];
    const float* w2   = (const float*)d_in[5];
    const float* b2   = (const float*)d_in[6];
    const float* w3   = (const float*)d_in[7];
    const float* b3   = (const float*)d_in[8];
    const float* fcw  = (const float*)d_in[9];
    const float* fcb  = (const float*)d_in[10];
    float* out = (float*)d_out;

    const int N = in_sizes[0];           // needs N <= 131072 (17-bit packing)
    const int E = in_sizes[1] / 2;
    const int G = out_size;
    const int H = 64;
    const int nbkt = (N + SBS - 1) / SBS;        // 196 superblocks
    const int NBLK = (N + NB - 1) / NB;          // 3125 gather blocks
    const int NBLKP = nbkt * 16;                 // padded bounds rows

    const int* src = ei;
    const int* dst = ei + E;

    char* p = (char*)d_ws;
    int*   bucketCnt   = (int*)p; p += WS_ALIGN(sizeof(int) * BKTMAX);
    int*   bucketStart = (int*)p; p += WS_ALIGN(sizeof(int) * (BKTMAX + 1));
    int*   gCursor     = (int*)p; p += WS_ALIGN(sizeof(int) * BKTMAX);
    int*   pkbuf       = (int*)p; p += WS_ALIGN(sizeof(int) * (size_t)E);
    int*   csr         = (int*)p; p += WS_ALIGN(sizeof(int) * ((size_t)E + 4));
    int*   boundsG     = (int*)p; p += WS_ALIGN(sizeof(int) * (size_t)NBLKP * (NBIN + 1));
    float* dinv        = (float*)p; p += WS_ALIGN(sizeof(float) * N);
    float* xs          = (float*)p; p += WS_ALIGN(sizeof(float) * N);
    unsigned short* bufA = (unsigned short*)p; p += WS_ALIGN(sizeof(unsigned short) * (size_t)N * H);
    unsigned short* bufB = (unsigned short*)p; p += WS_ALIGN(sizeof(unsigned short) * (size_t)N * H);
    float* dots        = (float*)p; p += WS_ALIGN(sizeof(float) * N);
    float* gsum        = (float*)p; p += WS_ALIGN(sizeof(float) * G);
    float* gcnt        = (float*)p; p += WS_ALIGN(sizeof(float) * G);

    const int B = 256;
    int gridZ    = ((G > BKTMAX ? G : BKTMAX) + B - 1) / B;
    int gridT    = (E + P1T - 1) / P1T;
    int gridG    = (G + B - 1) / B;
    int gridPool = (N + 1023) / 1024;
    int gridPers = 2048;
    if (gridPers * 4 > N) gridPers = (N + 3) / 4;

    k_zero<<<gridZ, B, 0, stream>>>(G, E, bucketCnt, gCursor, csr, gsum, gcnt);
    k_cnt1<<<gridT, B, 0, stream>>>(E, dst, bucketCnt);
    k_scanB<<<1, B, 0, stream>>>(nbkt, E, bucketCnt, bucketStart);
    k_p1<<<gridT, B, 0, stream>>>(E, src, dst, bucketStart, gCursor, pkbuf);
    k_p2<<<nbkt, B, 0, stream>>>(N, bucketStart, pkbuf, x, csr, boundsG, dinv, xs);
    // layer 1 (rank-1, fused persistent) -> bf16
    k_layer1<<<gridPers, B, 0, stream>>>(N, boundsG, csr, xs, dinv, w1, b1, bufA);
    // layer 2: fused gather + GEMM(w2) -> bf16
    k_gg_mid<<<NBLK, B, 0, stream>>>(N, boundsG, csr, bufA, dinv, w2, b2, bufB);
    // layer 3: fused gather + GEMM(w3) + fc dot -> dots (f32)
    k_gg_final<<<NBLK, B, 0, stream>>>(N, boundsG, csr, bufB, dinv, w3, b3, fcw, dots);
    // pooling + head
    k_pool<<<gridPool, B, 0, stream>>>(N, dots, batch, gsum, gcnt);
    k_out<<<gridG, B, 0, stream>>>(G, gsum, gcnt, fcb, out);
}

// Round 17
// 350.329 us; speedup vs baseline: 2.6420x; 1.1071x over previous
//
#include <hip/hip_runtime.h>
#include <hip/hip_bf16.h>

// GCN: 3x GCNConv(H=64) + global mean pool + linear head.
// Round 16 -> 17: 2-deep software-pipelined gather. Iteration n prefetches
// iteration n+1's csr quad AND its 8 bf16 row loads (separate h regs) before
// consuming the current g regs -> exposed miss latency ~halves. launch_bounds
// relaxed to (256,4): R14/R16 postmortem showed the (256,8) 64-VGPR cap made
// the compiler REUSE load registers (VGPR stayed 32), silently serializing
// intended MLP. Everything else unchanged from R16 (bf16 buffers, whole-row
// gather, p1/p2 build).

#define WS_ALIGN(x) (((x) + 255) & ~size_t(255))
#define NCHUNK 8
#define CSH 14           // chunk = src >> 14
#define NB 32            // dst rows per gather block
#define RPW (NB / 4)     // rows per wave = 8
#define NBIN (NB * NCHUNK)   // 256
#define USH 17
#define UMASK 0x1FFFF
#define BKTMAX 256
#define SBS 512
#define SBKEYS (SBS * NCHUNK)   // 4096
#define P1T 2048

__device__ __forceinline__ float bf2f(unsigned short h) {
    union { unsigned u; float f; } t;
    t.u = ((unsigned)h) << 16;
    return t.f;
}
__device__ __forceinline__ unsigned short f2bf(float f) {
    union { float f; unsigned u; } t;
    t.f = f;
    unsigned r = t.u + 0x7FFF + ((t.u >> 16) & 1);   // round-to-nearest-even
    return (unsigned short)(r >> 16);
}

__global__ __launch_bounds__(256) void k_zero(int g, int e, int* bucketCnt,
                                              int* gCursor, int* csr,
                                              float* gsum, float* gcnt) {
    int i = blockIdx.x * blockDim.x + threadIdx.x;
    if (i < BKTMAX) { bucketCnt[i] = 0; gCursor[i] = 0; }
    if (i < g) { gsum[i] = 0.f; gcnt[i] = 0.f; }
    if (i < 4) csr[e + i] = 0;
}

__global__ __launch_bounds__(256) void k_cnt1(int e, const int* __restrict__ dst,
                                              int* __restrict__ bucketCnt) {
    __shared__ int c[BKTMAX];
    int tid = threadIdx.x;
    c[tid] = 0;
    __syncthreads();
    int base = blockIdx.x * P1T;
#pragma unroll
    for (int q = 0; q < P1T / 256; ++q) {
        int i = base + q * 256 + tid;
        if (i < e) atomicAdd(&c[dst[i] >> 9], 1);
    }
    __syncthreads();
    if (c[tid] > 0) atomicAdd(&bucketCnt[tid], c[tid]);
}

__global__ __launch_bounds__(256) void k_scanB(int nbkt, int e,
                                               const int* __restrict__ bucketCnt,
                                               int* __restrict__ bucketStart) {
    __shared__ int sd[256];
    int tid = threadIdx.x;
    int v = (tid < nbkt) ? bucketCnt[tid] : 0;
    sd[tid] = v;
    __syncthreads();
    for (int off = 1; off < 256; off <<= 1) {
        int t = (tid >= off) ? sd[tid - off] : 0;
        __syncthreads();
        sd[tid] += t;
        __syncthreads();
    }
    if (tid < nbkt) bucketStart[tid] = sd[tid] - v;
    if (tid == 0) bucketStart[nbkt] = e;
}

// p1: tile sort by superblock, contiguous run writes of packed words
__global__ __launch_bounds__(256) void k_p1(int e, const int* __restrict__ src,
                                            const int* __restrict__ dst,
                                            const int* __restrict__ bucketStart,
                                            int* __restrict__ gCursor,
                                            int* __restrict__ pkbuf) {
    __shared__ int cnt[BKTMAX], exc[BKTMAX], cur[BKTMAX], bb[BKTMAX];
    __shared__ int sd[256];
    __shared__ int stage[P1T];
    __shared__ unsigned char stgb[P1T];
    int tid = threadIdx.x;
    cnt[tid] = 0;
    __syncthreads();
    int base = blockIdx.x * P1T;
    int m = e - base; if (m > P1T) m = P1T;
    int pk8[P1T / 256];
    int b8[P1T / 256];
#pragma unroll
    for (int q = 0; q < P1T / 256; ++q) {
        int li = q * 256 + tid;
        if (li < m) {
            int d = dst[base + li];
            int s = src[base + li];
            int b = d >> 9;
            b8[q] = b;
            pk8[q] = ((d & (SBS - 1)) << USH) | s;
            atomicAdd(&cnt[b], 1);
        }
    }
    __syncthreads();
    int cv = cnt[tid];
    sd[tid] = cv;
    __syncthreads();
    for (int off = 1; off < 256; off <<= 1) {
        int t = (tid >= off) ? sd[tid - off] : 0;
        __syncthreads();
        sd[tid] += t;
        __syncthreads();
    }
    exc[tid] = sd[tid] - cv;
    cur[tid] = sd[tid] - cv;
    if (cv > 0) bb[tid] = atomicAdd(&gCursor[tid], cv);
    __syncthreads();
#pragma unroll
    for (int q = 0; q < P1T / 256; ++q) {
        int li = q * 256 + tid;
        if (li < m) {
            int b = b8[q];
            int pos = atomicAdd(&cur[b], 1);
            stage[pos] = pk8[q];
            stgb[pos] = (unsigned char)b;
        }
    }
    __syncthreads();
#pragma unroll
    for (int q = 0; q < P1T / 256; ++q) {
        int p = q * 256 + tid;
        if (p < m) {
            int b = stgb[p];
            pkbuf[bucketStart[b] + bb[b] + (p - exc[b])] = stage[p];
        }
    }
}

// p2: per-superblock counting sort -> csr [row][chunk] + bounds + dinv/xs
__global__ __launch_bounds__(256) void k_p2(int n, const int* __restrict__ bucketStart,
                                            const int* __restrict__ pkbuf,
                                            const float* __restrict__ x,
                                            int* __restrict__ csr,
                                            int* __restrict__ boundsG,
                                            float* __restrict__ dinv,
                                            float* __restrict__ xs) {
    __shared__ int cnt[SBKEYS + 1];
    __shared__ int sd[256];
    int sb = blockIdx.x, tid = threadIdx.x;
    int r0 = bucketStart[sb], r1 = bucketStart[sb + 1];
    for (int k = tid; k < SBKEYS + 1; k += 256) cnt[k] = 0;
    __syncthreads();
    for (int i = r0 + tid; i < r1; i += 256) {
        int w = pkbuf[i];
        int key = ((w >> USH) << 3) | ((w & UMASK) >> CSH);
        atomicAdd(&cnt[key], 1);
    }
    __syncthreads();
    int base16 = tid * 16;
    int loc[16]; int s = 0;
#pragma unroll
    for (int j = 0; j < 16; ++j) { loc[j] = cnt[base16 + j]; s += loc[j]; }
    sd[tid] = s;
    __syncthreads();
    for (int off = 1; off < 256; off <<= 1) {
        int t = (tid >= off) ? sd[tid - off] : 0;
        __syncthreads();
        sd[tid] += t;
        __syncthreads();
    }
    int run = sd[tid] - s;
#pragma unroll
    for (int j = 0; j < 16; ++j) { cnt[base16 + j] = run; run += loc[j]; }
    if (tid == 255) cnt[SBKEYS] = run;
    __syncthreads();
    for (int k = tid; k < SBKEYS; k += 256) {
        int bi = sb * 16 + (k >> 8);
        boundsG[(size_t)bi * (NBIN + 1) + (k & 255)] = r0 + cnt[k];
    }
    if (tid < 16)
        boundsG[(size_t)(sb * 16 + tid) * (NBIN + 1) + NBIN] = r0 + cnt[(tid + 1) * 256];
    for (int dl = tid; dl < SBS; dl += 256) {
        int v = sb * SBS + dl;
        if (v < n) {
            int deg = cnt[dl * 8 + 8] - cnt[dl * 8] + 1;
            float di = 1.0f / sqrtf((float)deg);
            dinv[v] = di;
            xs[v] = x[v] * di;
        }
    }
    __syncthreads();
    for (int i = r0 + tid; i < r1; i += 256) {
        int w = pkbuf[i];
        int srcv = w & UMASK;
        int key = ((w >> USH) << 3) | (srcv >> CSH);
        int pos = atomicAdd(&cnt[key], 1);
        csr[r0 + pos] = srcv;
    }
}

// layer 1 fused (rank-1), persistent wave-per-node; bf16 output
__global__ __launch_bounds__(256, 8) void k_layer1(int n, const int* __restrict__ boundsG,
                                                   const int* __restrict__ csr,
                                                   const float* __restrict__ xs,
                                                   const float* __restrict__ dinv,
                                                   const float* __restrict__ w1,
                                                   const float* __restrict__ b1,
                                                   unsigned short* __restrict__ hs_out) {
    int tid = threadIdx.x;
    int r = tid >> 6, lane = tid & 63;
    float w1r = w1[lane], b1r = b1[lane];
    int wid = blockIdx.x * 4 + r;
    int stride = gridDim.x * 4;
    for (int v = wid; v < n; v += stride) {
        int bi = v / NB, vi = v & (NB - 1);
        size_t base = (size_t)bi * (NBIN + 1) + vi * NCHUNK;
        int s0 = boundsG[base], s1 = boundsG[base + NCHUNK];
        float acc = 0.f;
        for (int k = s0 + lane; k < s1; k += 64) acc += xs[csr[k]];
#pragma unroll
        for (int m = 32; m > 0; m >>= 1) acc += __shfl_xor(acc, m, 64);
        float dv = dinv[v];
        float s = (acc + xs[v]) * dv;
        hs_out[(size_t)v * 64 + lane] = f2bf(fmaxf(s * w1r + b1r, 0.f) * dv);
    }
}

// ---- fused whole-row gather (bf16, 2-deep software pipeline) + inline GEMM ----
#define GATHER_CORE                                                            \
    __shared__ float ws[64 * 64];                                              \
    __shared__ float rowl[4][64];                                              \
    __shared__ int bndL[NBIN + 1];                                             \
    int tid = threadIdx.x;                                                     \
    int lane = tid & 63;                                                       \
    int r = tid >> 6;                                                          \
    int v0 = blockIdx.x * NB;                                                  \
    for (int k = tid; k < 64 * 64; k += 256) ws[k] = w[k];                     \
    for (int i = tid; i < NBIN + 1; i += 256)                                  \
        bndL[i] = boundsG[(size_t)blockIdx.x * (NBIN + 1) + i];                \
    float acc[RPW];                                                            \
    _Pragma("unroll")                                                          \
    for (int q = 0; q < RPW; ++q) {                                            \
        int v = v0 + q * 4 + r;                                                \
        acc[q] = (v < n) ? bf2f(hs_in[(size_t)v * 64 + lane]) : 0.f;           \
    }                                                                          \
    __syncthreads();                                                           \
    _Pragma("unroll")                                                          \
    for (int t = 0; t < RPW / 2; ++t) {                                        \
        int viA = (2 * t) * 4 + r;                                             \
        int viB = (2 * t + 1) * 4 + r;                                         \
        int ba = __builtin_amdgcn_readfirstlane(bndL[viA * NCHUNK]);           \
        int a1 = __builtin_amdgcn_readfirstlane(bndL[viA * NCHUNK + NCHUNK]);  \
        int bb = __builtin_amdgcn_readfirstlane(bndL[viB * NCHUNK]);           \
        int b1_ = __builtin_amdgcn_readfirstlane(bndL[viB * NCHUNK + NCHUNK]); \
        int pa = (a1 - ba > 0) ? ba : bb;                                      \
        int pb = (b1_ - bb > 0) ? bb : ba;                                     \
        /* prologue: load first quads + first row data */                      \
        float gA0 = bf2f(hs_in[(size_t)csr[pa] * 64 + lane]);                  \
        float gA1 = bf2f(hs_in[(size_t)csr[pa + 1] * 64 + lane]);              \
        float gA2 = bf2f(hs_in[(size_t)csr[pa + 2] * 64 + lane]);              \
        float gA3 = bf2f(hs_in[(size_t)csr[pa + 3] * 64 + lane]);              \
        float gB0 = bf2f(hs_in[(size_t)csr[pb] * 64 + lane]);                  \
        float gB1 = bf2f(hs_in[(size_t)csr[pb + 1] * 64 + lane]);              \
        float gB2 = bf2f(hs_in[(size_t)csr[pb + 2] * 64 + lane]);              \
        float gB3 = bf2f(hs_in[(size_t)csr[pb + 3] * 64 + lane]);              \
        while (ba < a1 || bb < b1_) {                                          \
            int na = ba + 4, nb = bb + 4;                                      \
            int pa2 = (a1 - na > 0) ? na : ((b1_ - nb > 0) ? nb : pa);         \
            int pb2 = (b1_ - nb > 0) ? nb : ((a1 - na > 0) ? na : pb);         \
            /* prefetch next iteration's rows (independent of adds below) */   \
            float hA0 = bf2f(hs_in[(size_t)csr[pa2] * 64 + lane]);             \
            float hA1 = bf2f(hs_in[(size_t)csr[pa2 + 1] * 64 + lane]);         \
            float hA2 = bf2f(hs_in[(size_t)csr[pa2 + 2] * 64 + lane]);         \
            float hA3 = bf2f(hs_in[(size_t)csr[pa2 + 3] * 64 + lane]);         \
            float hB0 = bf2f(hs_in[(size_t)csr[pb2] * 64 + lane]);             \
            float hB1 = bf2f(hs_in[(size_t)csr[pb2 + 1] * 64 + lane]);         \
            float hB2 = bf2f(hs_in[(size_t)csr[pb2 + 2] * 64 + lane]);         \
            float hB3 = bf2f(hs_in[(size_t)csr[pb2 + 3] * 64 + lane]);         \
            /* consume current (g) with tail gating */                         \
            int remA = a1 - ba, remB = b1_ - bb;                               \
            if (remA >= 4) acc[2 * t] += (gA0 + gA1) + (gA2 + gA3);            \
            else if (remA > 0) {                                               \
                acc[2 * t] += gA0;                                             \
                if (remA > 1) acc[2 * t] += gA1;                               \
                if (remA > 2) acc[2 * t] += gA2;                               \
            }                                                                  \
            if (remB >= 4) acc[2 * t + 1] += (gB0 + gB1) + (gB2 + gB3);        \
            else if (remB > 0) {                                               \
                acc[2 * t + 1] += gB0;                                         \
                if (remB > 1) acc[2 * t + 1] += gB1;                           \
                if (remB > 2) acc[2 * t + 1] += gB2;                           \
            }                                                                  \
            gA0 = hA0; gA1 = hA1; gA2 = hA2; gA3 = hA3;                        \
            gB0 = hB0; gB1 = hB1; gB2 = hB2; gB3 = hB3;                        \
            pa = pa2; pb = pb2;                                                \
            ba = na; bb = nb;                                                  \
        }                                                                      \
    }

__global__ __launch_bounds__(256, 4) void k_gg_mid(int n,
                                                   const int* __restrict__ boundsG,
                                                   const int* __restrict__ csr,
                                                   const unsigned short* __restrict__ hs_in,
                                                   const float* __restrict__ dinv,
                                                   const float* __restrict__ w,
                                                   const float* __restrict__ b,
                                                   unsigned short* __restrict__ hs_out) {
    GATHER_CORE
    float breg = b[lane];
#pragma unroll 1
    for (int q = 0; q < RPW; ++q) {
        int v = v0 + q * 4 + r;
        if (v >= n) continue;
        float dv = dinv[v];
        rowl[r][lane] = acc[q] * dv;
        float o = breg;
#pragma unroll
        for (int k = 0; k < 64; ++k) o += rowl[r][k] * ws[k * 64 + lane];
        hs_out[(size_t)v * 64 + lane] = f2bf(fmaxf(o, 0.f) * dv);
    }
}

__global__ __launch_bounds__(256, 4) void k_gg_final(int n,
                                                     const int* __restrict__ boundsG,
                                                     const int* __restrict__ csr,
                                                     const unsigned short* __restrict__ hs_in,
                                                     const float* __restrict__ dinv,
                                                     const float* __restrict__ w,
                                                     const float* __restrict__ b,
                                                     const float* __restrict__ fcw,
                                                     float* __restrict__ dots) {
    GATHER_CORE
    float breg = b[lane];
    float freg = fcw[lane];
#pragma unroll 1
    for (int q = 0; q < RPW; ++q) {
        int v = v0 + q * 4 + r;
        if (v >= n) continue;
        float dv = dinv[v];
        rowl[r][lane] = acc[q] * dv;
        float o = breg;
#pragma unroll
        for (int k = 0; k < 64; ++k) o += rowl[r][k] * ws[k * 64 + lane];
        float val = fmaxf(o, 0.f) * freg;
#pragma unroll
        for (int m = 32; m > 0; m >>= 1) val += __shfl_xor(val, m, 64);
        if (lane == 0) dots[v] = val;
    }
}

// pooled accumulation: LDS-binned segmented reduce over sorted batch
__global__ __launch_bounds__(256) void k_pool(int n, const float* __restrict__ dots,
                                              const int* __restrict__ batch,
                                              float* __restrict__ gsum,
                                              float* __restrict__ gcnt) {
    __shared__ float ls[64], lc[64];
    __shared__ int gmin_s;
    int tid = threadIdx.x;
    int i0 = blockIdx.x * 1024;
    if (tid == 0) gmin_s = batch[i0];
    if (tid < 64) { ls[tid] = 0.f; lc[tid] = 0.f; }
    __syncthreads();
    int gmin = gmin_s;
#pragma unroll
    for (int c = 0; c < 4; ++c) {
        int i = i0 + c * 256 + tid;
        if (i < n) {
            int g = batch[i];
            float d = dots[i];
            int rr = g - gmin;
            if (rr < 64) {
                atomicAdd(&ls[rr], d);
                atomicAdd(&lc[rr], 1.f);
            } else {
                atomicAdd(&gsum[g], d);
                atomicAdd(&gcnt[g], 1.f);
            }
        }
    }
    __syncthreads();
    if (tid < 64 && lc[tid] != 0.f) {
        atomicAdd(&gsum[gmin + tid], ls[tid]);
        atomicAdd(&gcnt[gmin + tid], lc[tid]);
    }
}

__global__ __launch_bounds__(256) void k_out(int g, const float* __restrict__ gsum,
                                             const float* __restrict__ gcnt,
                                             const float* __restrict__ fcb,
                                             float* __restrict__ out) {
    int i = blockIdx.x * blockDim.x + threadIdx.x;
    if (i < g) out[i] = gsum[i] / fmaxf(gcnt[i], 1.f) + fcb[0];
}

extern "C" void kernel_launch(void* const* d_in, const int* in_sizes, int n_in,
                              void* d_out, int out_size, void* d_ws, size_t ws_size,
                              hipStream_t stream) {
    const float* x    = (const float*)d_in[0];
    const int*   ei   = (const int*)d_in[1];
    const int*   batch= (const int*)d_in[2];
    const float* w1   = (const float*)d_in[3];
    const float* b1   = (const float*)d_in[4];
    const float* w2   = (const float*)d_in[5];
    const float* b2   = (const float*)d_in[6];
    const float* w3   = (const float*)d_in[7];
    const float* b3   = (const float*)d_in[8];
    const float* fcw  = (const float*)d_in[9];
    const float* fcb  = (const float*)d_in[10];
    float* out = (float*)d_out;

    const int N = in_sizes[0];           // needs N <= 131072 (17-bit packing)
    const int E = in_sizes[1] / 2;
    const int G = out_size;
    const int H = 64;
    const int nbkt = (N + SBS - 1) / SBS;        // 196 superblocks
    const int NBLK = (N + NB - 1) / NB;          // 3125 gather blocks
    const int NBLKP = nbkt * 16;                 // padded bounds rows

    const int* src = ei;
    const int* dst = ei + E;

    char* p = (char*)d_ws;
    int*   bucketCnt   = (int*)p; p += WS_ALIGN(sizeof(int) * BKTMAX);
    int*   bucketStart = (int*)p; p += WS_ALIGN(sizeof(int) * (BKTMAX + 1));
    int*   gCursor     = (int*)p; p += WS_ALIGN(sizeof(int) * BKTMAX);
    int*   pkbuf       = (int*)p; p += WS_ALIGN(sizeof(int) * (size_t)E);
    int*   csr         = (int*)p; p += WS_ALIGN(sizeof(int) * ((size_t)E + 4));
    int*   boundsG     = (int*)p; p += WS_ALIGN(sizeof(int) * (size_t)NBLKP * (NBIN + 1));
    float* dinv        = (float*)p; p += WS_ALIGN(sizeof(float) * N);
    float* xs          = (float*)p; p += WS_ALIGN(sizeof(float) * N);
    unsigned short* bufA = (unsigned short*)p; p += WS_ALIGN(sizeof(unsigned short) * (size_t)N * H);
    unsigned short* bufB = (unsigned short*)p; p += WS_ALIGN(sizeof(unsigned short) * (size_t)N * H);
    float* dots        = (float*)p; p += WS_ALIGN(sizeof(float) * N);
    float* gsum        = (float*)p; p += WS_ALIGN(sizeof(float) * G);
    float* gcnt        = (float*)p; p += WS_ALIGN(sizeof(float) * G);

    const int B = 256;
    int gridZ    = ((G > BKTMAX ? G : BKTMAX) + B - 1) / B;
    int gridT    = (E + P1T - 1) / P1T;
    int gridG    = (G + B - 1) / B;
    int gridPool = (N + 1023) / 1024;
    int gridPers = 2048;
    if (gridPers * 4 > N) gridPers = (N + 3) / 4;

    k_zero<<<gridZ, B, 0, stream>>>(G, E, bucketCnt, gCursor, csr, gsum, gcnt);
    k_cnt1<<<gridT, B, 0, stream>>>(E, dst, bucketCnt);
    k_scanB<<<1, B, 0, stream>>>(nbkt, E, bucketCnt, bucketStart);
    k_p1<<<gridT, B, 0, stream>>>(E, src, dst, bucketStart, gCursor, pkbuf);
    k_p2<<<nbkt, B, 0, stream>>>(N, bucketStart, pkbuf, x, csr, boundsG, dinv, xs);
    // layer 1 (rank-1, fused persistent) -> bf16
    k_layer1<<<gridPers, B, 0, stream>>>(N, boundsG, csr, xs, dinv, w1, b1, bufA);
    // layer 2: fused gather + GEMM(w2) -> bf16
    k_gg_mid<<<NBLK, B, 0, stream>>>(N, boundsG, csr, bufA, dinv, w2, b2, bufB);
    // layer 3: fused gather + GEMM(w3) + fc dot -> dots (f32)
    k_gg_final<<<NBLK, B, 0, stream>>>(N, boundsG, csr, bufB, dinv, w3, b3, fcw, dots);
    // pooling + head
    k_pool<<<gridPool, B, 0, stream>>>(N, dots, batch, gsum, gcnt);
    k_out<<<gridG, B, 0, stream>>>(G, gsum, gcnt, fcb, out);
}

// Round 18
// 326.536 us; speedup vs baseline: 2.8345x; 1.0729x over previous
//
#include <hip/hip_runtime.h>
#include <hip/hip_bf16.h>

// GCN: 3x GCNConv(H=64) + global mean pool + linear head.
// Round 17 -> 18: packed-uint gather. bf16 row = 32 lanes x uint32, so the
// wave splits into halves (h=lane>>5): one uint load fetches TWO edges' rows
// (even/odd edges per half). Halves vmem instrs + addressing VALU; tail
// gating via masked FMA (rem>h, rem>2+h); halves merged by shfl_xor(32) at
// the epilogue. 2-deep pipeline retained. Everything else unchanged (bf16
// buffers, whole-row gather, p1/p2 build, (256,4) bounds).

#define WS_ALIGN(x) (((x) + 255) & ~size_t(255))
#define NCHUNK 8
#define CSH 14           // chunk = src >> 14
#define NB 32            // dst rows per gather block
#define RPW (NB / 4)     // rows per wave = 8
#define NBIN (NB * NCHUNK)   // 256
#define USH 17
#define UMASK 0x1FFFF
#define BKTMAX 256
#define SBS 512
#define SBKEYS (SBS * NCHUNK)   // 4096
#define P1T 2048

__device__ __forceinline__ float bf2f(unsigned short h) {
    union { unsigned u; float f; } t;
    t.u = ((unsigned)h) << 16;
    return t.f;
}
__device__ __forceinline__ unsigned short f2bf(float f) {
    union { float f; unsigned u; } t;
    t.f = f;
    unsigned r = t.u + 0x7FFF + ((t.u >> 16) & 1);   // round-to-nearest-even
    return (unsigned short)(r >> 16);
}
__device__ __forceinline__ float bfLo(unsigned v) {
    union { unsigned u; float f; } t;
    t.u = v << 16;
    return t.f;
}
__device__ __forceinline__ float bfHi(unsigned v) {
    union { unsigned u; float f; } t;
    t.u = v & 0xFFFF0000u;
    return t.f;
}

__global__ __launch_bounds__(256) void k_zero(int g, int e, int* bucketCnt,
                                              int* gCursor, int* csr,
                                              float* gsum, float* gcnt) {
    int i = blockIdx.x * blockDim.x + threadIdx.x;
    if (i < BKTMAX) { bucketCnt[i] = 0; gCursor[i] = 0; }
    if (i < g) { gsum[i] = 0.f; gcnt[i] = 0.f; }
    if (i < 4) csr[e + i] = 0;
}

__global__ __launch_bounds__(256) void k_cnt1(int e, const int* __restrict__ dst,
                                              int* __restrict__ bucketCnt) {
    __shared__ int c[BKTMAX];
    int tid = threadIdx.x;
    c[tid] = 0;
    __syncthreads();
    int base = blockIdx.x * P1T;
#pragma unroll
    for (int q = 0; q < P1T / 256; ++q) {
        int i = base + q * 256 + tid;
        if (i < e) atomicAdd(&c[dst[i] >> 9], 1);
    }
    __syncthreads();
    if (c[tid] > 0) atomicAdd(&bucketCnt[tid], c[tid]);
}

__global__ __launch_bounds__(256) void k_scanB(int nbkt, int e,
                                               const int* __restrict__ bucketCnt,
                                               int* __restrict__ bucketStart) {
    __shared__ int sd[256];
    int tid = threadIdx.x;
    int v = (tid < nbkt) ? bucketCnt[tid] : 0;
    sd[tid] = v;
    __syncthreads();
    for (int off = 1; off < 256; off <<= 1) {
        int t = (tid >= off) ? sd[tid - off] : 0;
        __syncthreads();
        sd[tid] += t;
        __syncthreads();
    }
    if (tid < nbkt) bucketStart[tid] = sd[tid] - v;
    if (tid == 0) bucketStart[nbkt] = e;
}

// p1: tile sort by superblock, contiguous run writes of packed words
__global__ __launch_bounds__(256) void k_p1(int e, const int* __restrict__ src,
                                            const int* __restrict__ dst,
                                            const int* __restrict__ bucketStart,
                                            int* __restrict__ gCursor,
                                            int* __restrict__ pkbuf) {
    __shared__ int cnt[BKTMAX], exc[BKTMAX], cur[BKTMAX], bb[BKTMAX];
    __shared__ int sd[256];
    __shared__ int stage[P1T];
    __shared__ unsigned char stgb[P1T];
    int tid = threadIdx.x;
    cnt[tid] = 0;
    __syncthreads();
    int base = blockIdx.x * P1T;
    int m = e - base; if (m > P1T) m = P1T;
    int pk8[P1T / 256];
    int b8[P1T / 256];
#pragma unroll
    for (int q = 0; q < P1T / 256; ++q) {
        int li = q * 256 + tid;
        if (li < m) {
            int d = dst[base + li];
            int s = src[base + li];
            int b = d >> 9;
            b8[q] = b;
            pk8[q] = ((d & (SBS - 1)) << USH) | s;
            atomicAdd(&cnt[b], 1);
        }
    }
    __syncthreads();
    int cv = cnt[tid];
    sd[tid] = cv;
    __syncthreads();
    for (int off = 1; off < 256; off <<= 1) {
        int t = (tid >= off) ? sd[tid - off] : 0;
        __syncthreads();
        sd[tid] += t;
        __syncthreads();
    }
    exc[tid] = sd[tid] - cv;
    cur[tid] = sd[tid] - cv;
    if (cv > 0) bb[tid] = atomicAdd(&gCursor[tid], cv);
    __syncthreads();
#pragma unroll
    for (int q = 0; q < P1T / 256; ++q) {
        int li = q * 256 + tid;
        if (li < m) {
            int b = b8[q];
            int pos = atomicAdd(&cur[b], 1);
            stage[pos] = pk8[q];
            stgb[pos] = (unsigned char)b;
        }
    }
    __syncthreads();
#pragma unroll
    for (int q = 0; q < P1T / 256; ++q) {
        int p = q * 256 + tid;
        if (p < m) {
            int b = stgb[p];
            pkbuf[bucketStart[b] + bb[b] + (p - exc[b])] = stage[p];
        }
    }
}

// p2: per-superblock counting sort -> csr [row][chunk] + bounds + dinv/xs
__global__ __launch_bounds__(256) void k_p2(int n, const int* __restrict__ bucketStart,
                                            const int* __restrict__ pkbuf,
                                            const float* __restrict__ x,
                                            int* __restrict__ csr,
                                            int* __restrict__ boundsG,
                                            float* __restrict__ dinv,
                                            float* __restrict__ xs) {
    __shared__ int cnt[SBKEYS + 1];
    __shared__ int sd[256];
    int sb = blockIdx.x, tid = threadIdx.x;
    int r0 = bucketStart[sb], r1 = bucketStart[sb + 1];
    for (int k = tid; k < SBKEYS + 1; k += 256) cnt[k] = 0;
    __syncthreads();
    for (int i = r0 + tid; i < r1; i += 256) {
        int w = pkbuf[i];
        int key = ((w >> USH) << 3) | ((w & UMASK) >> CSH);
        atomicAdd(&cnt[key], 1);
    }
    __syncthreads();
    int base16 = tid * 16;
    int loc[16]; int s = 0;
#pragma unroll
    for (int j = 0; j < 16; ++j) { loc[j] = cnt[base16 + j]; s += loc[j]; }
    sd[tid] = s;
    __syncthreads();
    for (int off = 1; off < 256; off <<= 1) {
        int t = (tid >= off) ? sd[tid - off] : 0;
        __syncthreads();
        sd[tid] += t;
        __syncthreads();
    }
    int run = sd[tid] - s;
#pragma unroll
    for (int j = 0; j < 16; ++j) { cnt[base16 + j] = run; run += loc[j]; }
    if (tid == 255) cnt[SBKEYS] = run;
    __syncthreads();
    for (int k = tid; k < SBKEYS; k += 256) {
        int bi = sb * 16 + (k >> 8);
        boundsG[(size_t)bi * (NBIN + 1) + (k & 255)] = r0 + cnt[k];
    }
    if (tid < 16)
        boundsG[(size_t)(sb * 16 + tid) * (NBIN + 1) + NBIN] = r0 + cnt[(tid + 1) * 256];
    for (int dl = tid; dl < SBS; dl += 256) {
        int v = sb * SBS + dl;
        if (v < n) {
            int deg = cnt[dl * 8 + 8] - cnt[dl * 8] + 1;
            float di = 1.0f / sqrtf((float)deg);
            dinv[v] = di;
            xs[v] = x[v] * di;
        }
    }
    __syncthreads();
    for (int i = r0 + tid; i < r1; i += 256) {
        int w = pkbuf[i];
        int srcv = w & UMASK;
        int key = ((w >> USH) << 3) | (srcv >> CSH);
        int pos = atomicAdd(&cnt[key], 1);
        csr[r0 + pos] = srcv;
    }
}

// layer 1 fused (rank-1), persistent wave-per-node; bf16 output
__global__ __launch_bounds__(256, 8) void k_layer1(int n, const int* __restrict__ boundsG,
                                                   const int* __restrict__ csr,
                                                   const float* __restrict__ xs,
                                                   const float* __restrict__ dinv,
                                                   const float* __restrict__ w1,
                                                   const float* __restrict__ b1,
                                                   unsigned short* __restrict__ hs_out) {
    int tid = threadIdx.x;
    int r = tid >> 6, lane = tid & 63;
    float w1r = w1[lane], b1r = b1[lane];
    int wid = blockIdx.x * 4 + r;
    int stride = gridDim.x * 4;
    for (int v = wid; v < n; v += stride) {
        int bi = v / NB, vi = v & (NB - 1);
        size_t base = (size_t)bi * (NBIN + 1) + vi * NCHUNK;
        int s0 = boundsG[base], s1 = boundsG[base + NCHUNK];
        float acc = 0.f;
        for (int k = s0 + lane; k < s1; k += 64) acc += xs[csr[k]];
#pragma unroll
        for (int m = 32; m > 0; m >>= 1) acc += __shfl_xor(acc, m, 64);
        float dv = dinv[v];
        float s = (acc + xs[v]) * dv;
        hs_out[(size_t)v * 64 + lane] = f2bf(fmaxf(s * w1r + b1r, 0.f) * dv);
    }
}

// ---- packed-uint whole-row gather (2 edges/load) + inline GEMM ----
// h = lane>>5 selects even/odd edges; fi = lane&31 is the uint feature pair.
// accLo/accHi per row-slot; halves merged by shfl_xor(32) at epilogue.
#define GATHER_CORE                                                            \
    __shared__ float ws[64 * 64];                                              \
    __shared__ float rowl[4][64];                                              \
    __shared__ int bndL[NBIN + 1];                                             \
    int tid = threadIdx.x;                                                     \
    int lane = tid & 63;                                                       \
    int r = tid >> 6;                                                          \
    int h = lane >> 5;                                                         \
    int fi = lane & 31;                                                        \
    int v0 = blockIdx.x * NB;                                                  \
    const unsigned* hsu = (const unsigned*)hs_in;                              \
    for (int k = tid; k < 64 * 64; k += 256) ws[k] = w[k];                     \
    for (int i = tid; i < NBIN + 1; i += 256)                                  \
        bndL[i] = boundsG[(size_t)blockIdx.x * (NBIN + 1) + i];                \
    float accLo[RPW], accHi[RPW];                                              \
    _Pragma("unroll")                                                          \
    for (int q = 0; q < RPW; ++q) {                                            \
        int v = v0 + q * 4 + r;                                                \
        unsigned sv = (v < n && h == 0) ? hsu[(size_t)v * 32 + fi] : 0u;       \
        accLo[q] = bfLo(sv);                                                   \
        accHi[q] = bfHi(sv);                                                   \
    }                                                                          \
    __syncthreads();                                                           \
    _Pragma("unroll")                                                          \
    for (int t = 0; t < RPW / 2; ++t) {                                        \
        int viA = (2 * t) * 4 + r;                                             \
        int viB = (2 * t + 1) * 4 + r;                                         \
        int ba = __builtin_amdgcn_readfirstlane(bndL[viA * NCHUNK]);           \
        int a1 = __builtin_amdgcn_readfirstlane(bndL[viA * NCHUNK + NCHUNK]);  \
        int bb = __builtin_amdgcn_readfirstlane(bndL[viB * NCHUNK]);           \
        int b1_ = __builtin_amdgcn_readfirstlane(bndL[viB * NCHUNK + NCHUNK]); \
        int pa = (a1 - ba > 0) ? ba : bb;                                      \
        int pb = (b1_ - bb > 0) ? bb : ba;                                     \
        /* prologue: first quads + first packed loads */                       \
        int uA0 = csr[pa], uA1 = csr[pa + 1], uA2 = csr[pa + 2], uA3 = csr[pa + 3]; \
        int uB0 = csr[pb], uB1 = csr[pb + 1], uB2 = csr[pb + 2], uB3 = csr[pb + 3]; \
        unsigned gA01 = hsu[(size_t)(h ? uA1 : uA0) * 32 + fi];                \
        unsigned gA23 = hsu[(size_t)(h ? uA3 : uA2) * 32 + fi];                \
        unsigned gB01 = hsu[(size_t)(h ? uB1 : uB0) * 32 + fi];                \
        unsigned gB23 = hsu[(size_t)(h ? uB3 : uB2) * 32 + fi];                \
        while (ba < a1 || bb < b1_) {                                          \
            int na = ba + 4, nb = bb + 4;                                      \
            int pa2 = (a1 - na > 0) ? na : ((b1_ - nb > 0) ? nb : pa);         \
            int pb2 = (b1_ - nb > 0) ? nb : ((a1 - na > 0) ? na : pb);         \
            /* prefetch next quads + next packed loads */                      \
            int vA0 = csr[pa2], vA1 = csr[pa2 + 1], vA2 = csr[pa2 + 2], vA3 = csr[pa2 + 3]; \
            int vB0 = csr[pb2], vB1 = csr[pb2 + 1], vB2 = csr[pb2 + 2], vB3 = csr[pb2 + 3]; \
            unsigned nA01 = hsu[(size_t)(h ? vA1 : vA0) * 32 + fi];            \
            unsigned nA23 = hsu[(size_t)(h ? vA3 : vA2) * 32 + fi];            \
            unsigned nB01 = hsu[(size_t)(h ? vB1 : vB0) * 32 + fi];            \
            unsigned nB23 = hsu[(size_t)(h ? vB3 : vB2) * 32 + fi];            \
            /* consume current with masked FMA tail gating */                  \
            int remA = a1 - ba, remB = b1_ - bb;                               \
            float mA0 = (remA > h) ? 1.f : 0.f;                                \
            float mA1 = (remA > 2 + h) ? 1.f : 0.f;                            \
            float mB0 = (remB > h) ? 1.f : 0.f;                                \
            float mB1 = (remB > 2 + h) ? 1.f : 0.f;                            \
            accLo[2 * t]     += bfLo(gA01) * mA0 + bfLo(gA23) * mA1;           \
            accHi[2 * t]     += bfHi(gA01) * mA0 + bfHi(gA23) * mA1;           \
            accLo[2 * t + 1] += bfLo(gB01) * mB0 + bfLo(gB23) * mB1;           \
            accHi[2 * t + 1] += bfHi(gB01) * mB0 + bfHi(gB23) * mB1;           \
            gA01 = nA01; gA23 = nA23; gB01 = nB01; gB23 = nB23;                \
            pa = pa2; pb = pb2;                                                \
            ba = na; bb = nb;                                                  \
        }                                                                      \
    }

__global__ __launch_bounds__(256, 4) void k_gg_mid(int n,
                                                   const int* __restrict__ boundsG,
                                                   const int* __restrict__ csr,
                                                   const unsigned short* __restrict__ hs_in,
                                                   const float* __restrict__ dinv,
                                                   const float* __restrict__ w,
                                                   const float* __restrict__ b,
                                                   unsigned short* __restrict__ hs_out) {
    GATHER_CORE
    float breg = b[lane];
#pragma unroll 1
    for (int q = 0; q < RPW; ++q) {
        int v = v0 + q * 4 + r;
        if (v >= n) continue;
        float dv = dinv[v];
        float lo = accLo[q]; lo += __shfl_xor(lo, 32, 64);
        float hi = accHi[q]; hi += __shfl_xor(hi, 32, 64);
        if (h == 0) {
            rowl[r][2 * fi] = lo * dv;
            rowl[r][2 * fi + 1] = hi * dv;
        }
        float o = breg;
#pragma unroll
        for (int k = 0; k < 64; ++k) o += rowl[r][k] * ws[k * 64 + lane];
        hs_out[(size_t)v * 64 + lane] = f2bf(fmaxf(o, 0.f) * dv);
    }
}

__global__ __launch_bounds__(256, 4) void k_gg_final(int n,
                                                     const int* __restrict__ boundsG,
                                                     const int* __restrict__ csr,
                                                     const unsigned short* __restrict__ hs_in,
                                                     const float* __restrict__ dinv,
                                                     const float* __restrict__ w,
                                                     const float* __restrict__ b,
                                                     const float* __restrict__ fcw,
                                                     float* __restrict__ dots) {
    GATHER_CORE
    float breg = b[lane];
    float freg = fcw[lane];
#pragma unroll 1
    for (int q = 0; q < RPW; ++q) {
        int v = v0 + q * 4 + r;
        if (v >= n) continue;
        float dv = dinv[v];
        float lo = accLo[q]; lo += __shfl_xor(lo, 32, 64);
        float hi = accHi[q]; hi += __shfl_xor(hi, 32, 64);
        if (h == 0) {
            rowl[r][2 * fi] = lo * dv;
            rowl[r][2 * fi + 1] = hi * dv;
        }
        float o = breg;
#pragma unroll
        for (int k = 0; k < 64; ++k) o += rowl[r][k] * ws[k * 64 + lane];
        float val = fmaxf(o, 0.f) * freg;
#pragma unroll
        for (int m = 32; m > 0; m >>= 1) val += __shfl_xor(val, m, 64);
        if (lane == 0) dots[v] = val;
    }
}

// pooled accumulation: LDS-binned segmented reduce over sorted batch
__global__ __launch_bounds__(256) void k_pool(int n, const float* __restrict__ dots,
                                              const int* __restrict__ batch,
                                              float* __restrict__ gsum,
                                              float* __restrict__ gcnt) {
    __shared__ float ls[64], lc[64];
    __shared__ int gmin_s;
    int tid = threadIdx.x;
    int i0 = blockIdx.x * 1024;
    if (tid == 0) gmin_s = batch[i0];
    if (tid < 64) { ls[tid] = 0.f; lc[tid] = 0.f; }
    __syncthreads();
    int gmin = gmin_s;
#pragma unroll
    for (int c = 0; c < 4; ++c) {
        int i = i0 + c * 256 + tid;
        if (i < n) {
            int g = batch[i];
            float d = dots[i];
            int rr = g - gmin;
            if (rr < 64) {
                atomicAdd(&ls[rr], d);
                atomicAdd(&lc[rr], 1.f);
            } else {
                atomicAdd(&gsum[g], d);
                atomicAdd(&gcnt[g], 1.f);
            }
        }
    }
    __syncthreads();
    if (tid < 64 && lc[tid] != 0.f) {
        atomicAdd(&gsum[gmin + tid], ls[tid]);
        atomicAdd(&gcnt[gmin + tid], lc[tid]);
    }
}

__global__ __launch_bounds__(256) void k_out(int g, const float* __restrict__ gsum,
                                             const float* __restrict__ gcnt,
                                             const float* __restrict__ fcb,
                                             float* __restrict__ out) {
    int i = blockIdx.x * blockDim.x + threadIdx.x;
    if (i < g) out[i] = gsum[i] / fmaxf(gcnt[i], 1.f) + fcb[0];
}

extern "C" void kernel_launch(void* const* d_in, const int* in_sizes, int n_in,
                              void* d_out, int out_size, void* d_ws, size_t ws_size,
                              hipStream_t stream) {
    const float* x    = (const float*)d_in[0];
    const int*   ei   = (const int*)d_in[1];
    const int*   batch= (const int*)d_in[2];
    const float* w1   = (const float*)d_in[3];
    const float* b1   = (const float*)d_in[4];
    const float* w2   = (const float*)d_in[5];
    const float* b2   = (const float*)d_in[6];
    const float* w3   = (const float*)d_in[7];
    const float* b3   = (const float*)d_in[8];
    const float* fcw  = (const float*)d_in[9];
    const float* fcb  = (const float*)d_in[10];
    float* out = (float*)d_out;

    const int N = in_sizes[0];           // needs N <= 131072 (17-bit packing)
    const int E = in_sizes[1] / 2;
    const int G = out_size;
    const int H = 64;
    const int nbkt = (N + SBS - 1) / SBS;        // 196 superblocks
    const int NBLK = (N + NB - 1) / NB;          // 3125 gather blocks
    const int NBLKP = nbkt * 16;                 // padded bounds rows

    const int* src = ei;
    const int* dst = ei + E;

    char* p = (char*)d_ws;
    int*   bucketCnt   = (int*)p; p += WS_ALIGN(sizeof(int) * BKTMAX);
    int*   bucketStart = (int*)p; p += WS_ALIGN(sizeof(int) * (BKTMAX + 1));
    int*   gCursor     = (int*)p; p += WS_ALIGN(sizeof(int) * BKTMAX);
    int*   pkbuf       = (int*)p; p += WS_ALIGN(sizeof(int) * (size_t)E);
    int*   csr         = (int*)p; p += WS_ALIGN(sizeof(int) * ((size_t)E + 4));
    int*   boundsG     = (int*)p; p += WS_ALIGN(sizeof(int) * (size_t)NBLKP * (NBIN + 1));
    float* dinv        = (float*)p; p += WS_ALIGN(sizeof(float) * N);
    float* xs          = (float*)p; p += WS_ALIGN(sizeof(float) * N);
    unsigned short* bufA = (unsigned short*)p; p += WS_ALIGN(sizeof(unsigned short) * (size_t)N * H);
    unsigned short* bufB = (unsigned short*)p; p += WS_ALIGN(sizeof(unsigned short) * (size_t)N * H);
    float* dots        = (float*)p; p += WS_ALIGN(sizeof(float) * N);
    float* gsum        = (float*)p; p += WS_ALIGN(sizeof(float) * G);
    float* gcnt        = (float*)p; p += WS_ALIGN(sizeof(float) * G);

    const int B = 256;
    int gridZ    = ((G > BKTMAX ? G : BKTMAX) + B - 1) / B;
    int gridT    = (E + P1T - 1) / P1T;
    int gridG    = (G + B - 1) / B;
    int gridPool = (N + 1023) / 1024;
    int gridPers = 2048;
    if (gridPers * 4 > N) gridPers = (N + 3) / 4;

    k_zero<<<gridZ, B, 0, stream>>>(G, E, bucketCnt, gCursor, csr, gsum, gcnt);
    k_cnt1<<<gridT, B, 0, stream>>>(E, dst, bucketCnt);
    k_scanB<<<1, B, 0, stream>>>(nbkt, E, bucketCnt, bucketStart);
    k_p1<<<gridT, B, 0, stream>>>(E, src, dst, bucketStart, gCursor, pkbuf);
    k_p2<<<nbkt, B, 0, stream>>>(N, bucketStart, pkbuf, x, csr, boundsG, dinv, xs);
    // layer 1 (rank-1, fused persistent) -> bf16
    k_layer1<<<gridPers, B, 0, stream>>>(N, boundsG, csr, xs, dinv, w1, b1, bufA);
    // layer 2: fused gather + GEMM(w2) -> bf16
    k_gg_mid<<<NBLK, B, 0, stream>>>(N, boundsG, csr, bufA, dinv, w2, b2, bufB);
    // layer 3: fused gather + GEMM(w3) + fc dot -> dots (f32)
    k_gg_final<<<NBLK, B, 0, stream>>>(N, boundsG, csr, bufB, dinv, w3, b3, fcw, dots);
    // pooling + head
    k_pool<<<gridPool, B, 0, stream>>>(N, dots, batch, gsum, gcnt);
    k_out<<<gridG, B, 0, stream>>>(G, gsum, gcnt, fcb, out);
}